// Round 6
// baseline (271.292 us; speedup 1.0000x reference)
//
#include <hip/hip_runtime.h>

typedef unsigned short u16;
typedef __attribute__((ext_vector_type(8))) short v8s;
typedef __attribute__((ext_vector_type(4))) float v4f;

#define S_LEN 2048
#define HID   2048
#define NH    32
#define NKV   8
#define HD    64
#define DVV   128
#define LAMBDA_INIT  0.7455692280263525f
#define ONE_MINUS_LI 0.2544307719736475f

__device__ __forceinline__ u16 f2b(float f){
  union { float f; unsigned int i; } v; v.f = f;
  unsigned int x = v.i;
  unsigned int r = (x + 0x7fffu + ((x >> 16) & 1u)) >> 16;
  return (u16)r;
}
__device__ __forceinline__ float b2f(u16 u){
  union { unsigned int i; float f; } v; v.i = ((unsigned int)u) << 16; return v.f;
}

__device__ __forceinline__ void gld16(const u16* g, u16* l){
  __builtin_amdgcn_global_load_lds(
      (const __attribute__((address_space(1))) unsigned int*)g,
      (__attribute__((address_space(3))) unsigned int*)l, 16, 0, 0);
}

// one launch casting hs, Wq, Wk, Wv, Wo to bf16 (regions by blockIdx)
__global__ __launch_bounds__(256) void cast5(
    const float* __restrict__ hs, const float* __restrict__ Wq,
    const float* __restrict__ Wk, const float* __restrict__ Wv,
    const float* __restrict__ Wo,
    u16* __restrict__ hsb, u16* __restrict__ Wqkvb, u16* __restrict__ Wob)
{
  int b = blockIdx.x;
  const float* S; u16* D; int rb;
  if (b < 2048)      { S = hs; D = hsb;             rb = b; }
  else if (b < 4096) { S = Wq; D = Wqkvb;           rb = b - 2048; }
  else if (b < 4608) { S = Wk; D = Wqkvb + 4194304; rb = b - 4096; }
  else if (b < 5120) { S = Wv; D = Wqkvb + 5242880; rb = b - 4608; }
  else               { S = Wo; D = Wob;             rb = b - 5120; }
  size_t i = ((size_t)rb * 256 + threadIdx.x) * 8;
  float4 a = *(const float4*)(S + i);
  float4 c = *(const float4*)(S + i + 4);
  u16 o[8] = {f2b(a.x), f2b(a.y), f2b(a.z), f2b(a.w), f2b(c.x), f2b(c.y), f2b(c.z), f2b(c.w)};
  *(uint4*)(D + i) = *(const uint4*)o;
}

// C[m][n] = sum_k A[m*K+k]*B[n*K+k]; A,B bf16; C fp32 or bf16. 128x128 tile, BK=64,
// global_load_lds staging with XOR chunk swizzle (row&7).
template<int OUT_BF16>
__global__ __launch_bounds__(256) void gemm_bf16(const u16* __restrict__ A, const u16* __restrict__ B,
                                                 void* __restrict__ Cv, int M, int N, int K)
{
  __shared__ __attribute__((aligned(16))) u16 As[128*64];
  __shared__ __attribute__((aligned(16))) u16 Bs[128*64];
  const int t    = threadIdx.x;
  const int w    = t >> 6, lane = t & 63;
  const int mm   = lane & 15, g = lane >> 4;
  const int wr   = w >> 1, wc = w & 1;
  const int m0   = blockIdx.y * 128, n0 = blockIdx.x * 128;
  const int srow = w*32 + (lane >> 3);
  const int sch  = lane & 7;

  v4f acc[4][4];
#pragma unroll
  for (int i = 0; i < 4; i++)
#pragma unroll
    for (int j = 0; j < 4; j++) acc[i][j] = (v4f){0.f,0.f,0.f,0.f};

  for (int k0 = 0; k0 < K; k0 += 64){
    __syncthreads();
#pragma unroll
    for (int i = 0; i < 4; i++){
      int r  = srow + i*8;
      int ce = ((sch ^ (r & 7)) * 8);
      gld16(A + (size_t)(m0 + r) * K + k0 + ce, &As[w*2048 + i*512]);
      gld16(B + (size_t)(n0 + r) * K + k0 + ce, &Bs[w*2048 + i*512]);
    }
    __syncthreads();
#pragma unroll
    for (int kc = 0; kc < 2; kc++){
      v8s af[4], bf[4];
#pragma unroll
      for (int i = 0; i < 4; i++){
        int r = wr*64 + i*16 + mm;
        af[i] = *(const v8s*)&As[r*64 + (((kc*4 + g) ^ (r & 7)) * 8)];
      }
#pragma unroll
      for (int j = 0; j < 4; j++){
        int r = wc*64 + j*16 + mm;
        bf[j] = *(const v8s*)&Bs[r*64 + (((kc*4 + g) ^ (r & 7)) * 8)];
      }
#pragma unroll
      for (int i = 0; i < 4; i++)
#pragma unroll
        for (int j = 0; j < 4; j++)
          acc[i][j] = __builtin_amdgcn_mfma_f32_16x16x32_bf16(af[i], bf[j], acc[i][j], 0, 0, 0);
    }
  }
  if (OUT_BF16){
    u16* C = (u16*)Cv;
#pragma unroll
    for (int i = 0; i < 4; i++)
#pragma unroll
      for (int j = 0; j < 4; j++)
#pragma unroll
        for (int r = 0; r < 4; r++)
          C[(size_t)(m0 + wr*64 + i*16 + g*4 + r) * N + n0 + wc*64 + j*16 + mm] = f2b(acc[i][j][r]);
  } else {
    float* C = (float*)Cv;
#pragma unroll
    for (int i = 0; i < 4; i++)
#pragma unroll
      for (int j = 0; j < 4; j++)
#pragma unroll
        for (int r = 0; r < 4; r++)
          C[(size_t)(m0 + wr*64 + i*16 + g*4 + r) * N + n0 + wc*64 + j*16 + mm] = acc[i][j][r];
  }
}

// rope for Q (blocks 0..8191) and K (8192..10239) in one launch; bf16 in/out
__global__ __launch_bounds__(256) void rope_all(const u16* __restrict__ QKVb,
    const float* __restrict__ cosb, const float* __restrict__ sinb,
    u16* __restrict__ Qbf, u16* __restrict__ Kbf)
{
  int b = blockIdx.x;
  int d, h, s;
  const u16* src; u16* dst;
  if (b < 8192){
    int idx = b * 256 + threadIdx.x;
    d = idx & 31; h = (idx >> 5) & 31; s = idx >> 10;
    src = QKVb + (size_t)s * 3072 + h * HD + d;
    dst = Qbf + ((size_t)h * S_LEN + s) * HD + d;
  } else {
    int idx = (b - 8192) * 256 + threadIdx.x;
    d = idx & 31; h = (idx >> 5) & 7; s = idx >> 8;
    src = QKVb + (size_t)s * 3072 + 2048 + h * HD + d;
    dst = Kbf + ((size_t)h * S_LEN + s) * HD + d;
  }
  float c1 = cosb[s * HD + d],      s1 = sinb[s * HD + d];
  float c2 = cosb[s * HD + d + 32], s2 = sinb[s * HD + d + 32];
  float x1 = b2f(src[0]), x2 = b2f(src[32]);
  dst[0]  = f2b(x1 * c1 - x2 * s1);
  dst[32] = f2b(x2 * c2 + x1 * s2);
}

// V bf16 rows (stride u16 elems, head h at col h*64) -> Vt bf16 (8, 64, S)
__global__ __launch_bounds__(256) void vtrans(const u16* __restrict__ Vb, int stride, u16* __restrict__ Vt)
{
  __shared__ u16 T[64][72];
  const int b = blockIdx.x;
  const int h = b >> 5;
  const int s0 = (b & 31) * 64;
  const int t = threadIdx.x;
#pragma unroll
  for (int i = 0; i < 4; i++){
    int u = t + i * 256;
    int r = u >> 4, c4 = (u & 15) * 4;
    uint2 v = *(const uint2*)&Vb[(size_t)(s0 + r) * stride + h * HD + c4];
    T[c4+0][r] = (u16)(v.x & 0xffff); T[c4+1][r] = (u16)(v.x >> 16);
    T[c4+2][r] = (u16)(v.y & 0xffff); T[c4+3][r] = (u16)(v.y >> 16);
  }
  __syncthreads();
#pragma unroll
  for (int i = 0; i < 2; i++){
    int u = t + i * 256;
    int d = u >> 3, ch = (u & 7) * 8;
    *(uint4*)&Vt[((size_t)h * HD + d) * S_LEN + s0 + ch] = *(const uint4*)&T[d][ch];
  }
}

// Fused differential flash attention, 1024 threads / 16 waves per block.
// Grid (16,16) unchanged (256 blocks, 1 block/CU): block (d,hp) processes a
// DOUBLE q-tile (rows d*128..d*128+127) for heads hp (waves 0-7) and hp+16
// (waves 8-15). 16 waves = 4 waves/SIMD (2x the TLP of the 512-thr version)
// and K/V staging is shared across 2x the q-rows (half the fetch traffic).
// K-loop runs to kmax = q0+64; last two iters apply the generalized causal
// mask kof + col > qrow_local (kof = k0-q0 in {0,64}); lower-tile waves are
// fully masked on the extra iter (correct, 1 wasted iter for half the waves).
// V double-buffered, staged one full iteration ahead with K; no mid barrier
// (P is wave-private); per-iter sync is raw vmcnt(0)+s_barrier.
// Epilogue: head-b waves deposit Ob*lam/lb into fp32 OLDS (128x128, exactly
// overlaying the dead K+V buffers), head-a waves do diff+RMS+scale -> Ctx.
__global__ __launch_bounds__(1024, 4) void attn_fused(
    const u16* __restrict__ Qbf, const u16* __restrict__ Kbf, const u16* __restrict__ Vt,
    const float* __restrict__ lq1, const float* __restrict__ lk1,
    const float* __restrict__ lq2, const float* __restrict__ lk2,
    u16* __restrict__ Ctx)
{
  __shared__ __attribute__((aligned(16))) u16 SM[51200];   // 102400 B
  u16* QPa = SM;                  // 128 x 72 (Q then P, head a)
  u16* QPb = SM + 9216;           // 128 x 72 (head b)
  u16* Ksf = SM + 18432;          // [head:2][stage:2][64][64] u16 (32 KiB)
  u16* Vs  = SM + 34816;          // [stage:2][128][64] u16 (32 KiB)
  float* OLDS = (float*)(SM + 18432);  // 128 x 128 fp32 = 65536 B, overlays Ks+Vs

  const int d   = blockIdx.x;                 // 0..15 double-tile index
  const int hp  = blockIdx.y;                 // 0..15
  const int kva = hp >> 2, kvb = kva + 4;
  const int t   = threadIdx.x, w = t >> 6, lane = t & 63;
  const int hb  = w >> 3;                     // 0 = head a (waves 0-7), 1 = head b
  const int wq  = w & 7;                      // q-row group (16 rows each, 128 total)
  const int mm  = lane & 15, g = lane >> 4, g8 = g * 8;
  const int sr  = t >> 3;                     // staging row 0..127
  const int sc  = t & 7;
  const int so  = sc * 8;
  const int x0  = ((g ^ (mm & 7)) * 8);
  const int x1  = (((g + 4) ^ (mm & 7)) * 8);
  // staging constants: one K chunk + one V chunk per thread per tile
  const int khd  = (sr >> 6) ? kvb : kva;     // kv head for this thread's row
  const int rloc = sr & 63;                   // row within head
  const int ce   = ((sc ^ (sr & 7)) * 8);     // XOR chunk swizzle (matches x0/x1 reads)
  u16* kdst = Ksf + (w >> 3) * 8192 + ((w & 7) * 8) * 64;  // wave-uniform; + buf*4096
  u16* vdst = Vs + (w * 8) * 64;                            // wave-uniform; + buf*8192

  u16* QP = hb ? QPb : QPa;

  float lp1 = lq1[lane] * lk1[lane];
  float lp2 = lq2[lane] * lk2[lane];
#pragma unroll
  for (int off = 1; off < 64; off <<= 1){
    lp1 += __shfl_xor(lp1, off);
    lp2 += __shfl_xor(lp2, off);
  }
  const float lam = __expf(lp1) - __expf(lp2) + LAMBDA_INIT;

  const int q0   = d * 128;
  const int kmax = q0 + 64;                   // last k-tile start

  // prologue: issue K(0), V(0) into buffer 0; stage Q double-tiles
  gld16(Kbf + ((size_t)khd * S_LEN + rloc) * HD + ce, kdst);
  gld16(Vt  + ((size_t)khd * HD + rloc) * S_LEN + ce, vdst);
  *(uint4*)&QPa[sr*72 + so] = *(const uint4*)&Qbf[((size_t)hp        * S_LEN + q0 + sr) * HD + so];
  *(uint4*)&QPb[sr*72 + so] = *(const uint4*)&Qbf[((size_t)(hp + 16) * S_LEN + q0 + sr) * HD + so];
  __syncthreads();   // Q visible, K(0)/V(0) drained
  v8s qa0 = *(const v8s*)&QP[(wq*16 + mm)*72 + g8];
  v8s qa1 = *(const v8s*)&QP[(wq*16 + mm)*72 + 32 + g8];

  v4f O[8];
#pragma unroll
  for (int n = 0; n < 8; n++) O[n] = (v4f){0.f,0.f,0.f,0.f};
  float l[4] = {0.f,0.f,0.f,0.f};

  for (int k0 = 0; k0 <= kmax; k0 += 64){
    const int cur = (k0 >> 6) & 1;
    if (k0){
      // K(k0),V(k0) issued one full iteration ago: drain (≈0 stall), then sync.
      asm volatile("s_waitcnt vmcnt(0)" ::: "memory");
      __builtin_amdgcn_s_barrier();
      __builtin_amdgcn_sched_barrier(0);
    }
    // prefetch K(k0+64), V(k0+64) into the other buffers; in flight all iter
    if (k0 + 64 <= kmax){
      gld16(Vt  + ((size_t)khd * HD + rloc) * S_LEN + k0 + 64 + ce, vdst + (cur^1)*8192);
      gld16(Kbf + ((size_t)khd * S_LEN + k0 + 64 + rloc) * HD + ce, kdst + (cur^1)*4096);
    }

    const u16* Kh = Ksf + hb*8192 + cur*4096;
    const int kof = k0 - q0;                  // >= 0 only on last two iters
    const bool dg = (kof >= 0);
    v4f S[4];
#pragma unroll
    for (int n = 0; n < 4; n++){
      int row = n*16 + mm;
      v8s kb0 = *(const v8s*)&Kh[row*64 + x0];
      v8s kb1 = *(const v8s*)&Kh[row*64 + x1];
      v4f z = (v4f){0.f,0.f,0.f,0.f};
      z = __builtin_amdgcn_mfma_f32_16x16x32_bf16(qa0, kb0, z, 0, 0, 0);
      z = __builtin_amdgcn_mfma_f32_16x16x32_bf16(qa1, kb1, z, 0, 0, 0);
      S[n] = z;
    }
    // P is wave-private (rows wq*16..wq*16+15): no barrier around store/reload
#pragma unroll
    for (int n = 0; n < 4; n++)
#pragma unroll
      for (int r = 0; r < 4; r++){
        float pe = __expf(S[n][r] * 0.125f);
        if (dg && (kof + n*16 + mm > wq*16 + g*4 + r)) pe = 0.f;
        l[r] += pe;
        QP[(wq*16 + g*4 + r)*72 + n*16 + mm] = f2b(pe);
      }
    v8s pa0 = *(const v8s*)&QP[(wq*16 + mm)*72 + g8];
    v8s pa1 = *(const v8s*)&QP[(wq*16 + mm)*72 + 32 + g8];
    const u16* Vh = Vs + cur*8192;
#pragma unroll
    for (int n = 0; n < 8; n++){
      int row = n*16 + mm;
      v8s vb0 = *(const v8s*)&Vh[row*64 + x0];
      v8s vb1 = *(const v8s*)&Vh[row*64 + x1];
      O[n] = __builtin_amdgcn_mfma_f32_16x16x32_bf16(pa0, vb0, O[n], 0, 0, 0);
      O[n] = __builtin_amdgcn_mfma_f32_16x16x32_bf16(pa1, vb1, O[n], 0, 0, 0);
    }
  }

  // ---- epilogue ----
#pragma unroll
  for (int off = 1; off < 16; off <<= 1)
#pragma unroll
    for (int r = 0; r < 4; r++)
      l[r] += __shfl_xor(l[r], off);
  float il[4];
#pragma unroll
  for (int r = 0; r < 4; r++) il[r] = hb ? (lam / l[r]) : (1.0f / l[r]);

  __syncthreads();   // all QK/PV reads of Ks/Vs done; OLDS may overwrite them
  if (hb){
#pragma unroll
    for (int n = 0; n < 8; n++)
#pragma unroll
      for (int r = 0; r < 4; r++)
        OLDS[(wq*16 + g*4 + r)*128 + n*16 + mm] = O[n][r] * il[r];
  }
  __syncthreads();
  if (!hb){
    float av[8][4];
    float ss[4] = {0.f,0.f,0.f,0.f};
#pragma unroll
    for (int n = 0; n < 8; n++)
#pragma unroll
      for (int r = 0; r < 4; r++){
        float a = O[n][r] * il[r] - OLDS[(wq*16 + g*4 + r)*128 + n*16 + mm];
        av[n][r] = a;
        ss[r] += a * a;
      }
#pragma unroll
    for (int off = 1; off < 16; off <<= 1)
#pragma unroll
      for (int r = 0; r < 4; r++)
        ss[r] += __shfl_xor(ss[r], off);
    float rv[4];
#pragma unroll
    for (int r = 0; r < 4; r++)
      rv[r] = rsqrtf(ss[r] * (1.0f/128.0f) + 1e-6f) * ONE_MINUS_LI;
#pragma unroll
    for (int n = 0; n < 8; n++)
#pragma unroll
      for (int r = 0; r < 4; r++){
        int srow = q0 + wq*16 + g*4 + r;
        Ctx[(size_t)srow * HID + hp * DVV + n*16 + mm] = f2b(av[n][r] * rv[r]);
      }
  }
}

extern "C" void kernel_launch(void* const* d_in, const int* in_sizes, int n_in,
                              void* d_out, int out_size, void* d_ws, size_t ws_size,
                              hipStream_t stream)
{
  (void)in_sizes; (void)n_in; (void)out_size; (void)ws_size;
  const float* hs   = (const float*)d_in[0];
  const float* cosb = (const float*)d_in[1];
  const float* sinb = (const float*)d_in[2];
  const float* Wq   = (const float*)d_in[3];
  const float* Wk   = (const float*)d_in[4];
  const float* Wv   = (const float*)d_in[5];
  const float* Wo   = (const float*)d_in[6];
  const float* lq1  = (const float*)d_in[7];
  const float* lk1  = (const float*)d_in[8];
  const float* lq2  = (const float*)d_in[9];
  const float* lk2  = (const float*)d_in[10];

  char* ws = (char*)d_ws;
  u16* hsb   = (u16*)(ws);                   // [0,8) MB bf16 hs
  u16* Wqkvb = (u16*)(ws + (8u  << 20));     // [8,20) bf16 [Wq;Wk;Wv] 3072x2048
  u16* QKVb  = (u16*)(ws + (20u << 20));     // [20,32) bf16 (S,3072)
  u16* Ctx   = (u16*)(ws + (20u << 20));     // [20,28) overlays QKVb after rope/vtrans
  u16* Wob   = (u16*)(ws + (32u << 20));     // [32,40) bf16 Wo
  u16* Kbf   = (u16*)(ws + (44u << 20));     // [44,46) bf16 (8,S,64)
  u16* Vt    = (u16*)(ws + (46u << 20));     // [46,48) bf16 (8,64,S)
  u16* Qbf   = (u16*)(ws + (48u << 20));     // [48,56) bf16 (32,S,64)

  cast5<<<7168, 256, 0, stream>>>(hs, Wq, Wk, Wv, Wo, hsb, Wqkvb, Wob);
  gemm_bf16<1><<<dim3(24, 16), 256, 0, stream>>>(hsb, Wqkvb, QKVb, S_LEN, 3072, HID);
  rope_all<<<10240, 256, 0, stream>>>(QKVb, cosb, sinb, Qbf, Kbf);
  vtrans<<<NKV * (S_LEN/64), 256, 0, stream>>>(QKVb + 2560, 3072, Vt);
  attn_fused<<<dim3(16, 16), 1024, 0, stream>>>(Qbf, Kbf, Vt, lq1, lk1, lq2, lk2, Ctx);
  gemm_bf16<0><<<dim3(16, 16), 256, 0, stream>>>(Ctx, Wob, (float*)d_out, S_LEN, 2048, HID);
}

// Round 7
// 251.520 us; speedup vs baseline: 1.0786x; 1.0786x over previous
//
#include <hip/hip_runtime.h>

typedef unsigned short u16;
typedef __attribute__((ext_vector_type(8))) short v8s;
typedef __attribute__((ext_vector_type(4))) float v4f;

#define S_LEN 2048
#define HID   2048
#define NH    32
#define NKV   8
#define HD    64
#define DVV   128
#define LAMBDA_INIT  0.7455692280263525f
#define ONE_MINUS_LI 0.2544307719736475f

__device__ __forceinline__ u16 f2b(float f){
  union { float f; unsigned int i; } v; v.f = f;
  unsigned int x = v.i;
  unsigned int r = (x + 0x7fffu + ((x >> 16) & 1u)) >> 16;
  return (u16)r;
}
__device__ __forceinline__ float b2f(u16 u){
  union { unsigned int i; float f; } v; v.i = ((unsigned int)u) << 16; return v.f;
}

__device__ __forceinline__ void gld16(const u16* g, u16* l){
  __builtin_amdgcn_global_load_lds(
      (const __attribute__((address_space(1))) unsigned int*)g,
      (__attribute__((address_space(3))) unsigned int*)l, 16, 0, 0);
}

// one launch casting hs, Wq, Wk, Wv, Wo to bf16 (regions by blockIdx)
__global__ __launch_bounds__(256) void cast5(
    const float* __restrict__ hs, const float* __restrict__ Wq,
    const float* __restrict__ Wk, const float* __restrict__ Wv,
    const float* __restrict__ Wo,
    u16* __restrict__ hsb, u16* __restrict__ Wqkvb, u16* __restrict__ Wob)
{
  int b = blockIdx.x;
  const float* S; u16* D; int rb;
  if (b < 2048)      { S = hs; D = hsb;             rb = b; }
  else if (b < 4096) { S = Wq; D = Wqkvb;           rb = b - 2048; }
  else if (b < 4608) { S = Wk; D = Wqkvb + 4194304; rb = b - 4096; }
  else if (b < 5120) { S = Wv; D = Wqkvb + 5242880; rb = b - 4608; }
  else               { S = Wo; D = Wob;             rb = b - 5120; }
  size_t i = ((size_t)rb * 256 + threadIdx.x) * 8;
  float4 a = *(const float4*)(S + i);
  float4 c = *(const float4*)(S + i + 4);
  u16 o[8] = {f2b(a.x), f2b(a.y), f2b(a.z), f2b(a.w), f2b(c.x), f2b(c.y), f2b(c.z), f2b(c.w)};
  *(uint4*)(D + i) = *(const uint4*)o;
}

// C[m][n] = sum_k A[m*K+k]*B[n*K+k]; A,B bf16; C fp32 or bf16. 128x128 tile, BK=64,
// global_load_lds staging with XOR chunk swizzle (row&7).
template<int OUT_BF16>
__global__ __launch_bounds__(256) void gemm_bf16(const u16* __restrict__ A, const u16* __restrict__ B,
                                                 void* __restrict__ Cv, int M, int N, int K)
{
  __shared__ __attribute__((aligned(16))) u16 As[128*64];
  __shared__ __attribute__((aligned(16))) u16 Bs[128*64];
  const int t    = threadIdx.x;
  const int w    = t >> 6, lane = t & 63;
  const int mm   = lane & 15, g = lane >> 4;
  const int wr   = w >> 1, wc = w & 1;
  const int m0   = blockIdx.y * 128, n0 = blockIdx.x * 128;
  const int srow = w*32 + (lane >> 3);
  const int sch  = lane & 7;

  v4f acc[4][4];
#pragma unroll
  for (int i = 0; i < 4; i++)
#pragma unroll
    for (int j = 0; j < 4; j++) acc[i][j] = (v4f){0.f,0.f,0.f,0.f};

  for (int k0 = 0; k0 < K; k0 += 64){
    __syncthreads();
#pragma unroll
    for (int i = 0; i < 4; i++){
      int r  = srow + i*8;
      int ce = ((sch ^ (r & 7)) * 8);
      gld16(A + (size_t)(m0 + r) * K + k0 + ce, &As[w*2048 + i*512]);
      gld16(B + (size_t)(n0 + r) * K + k0 + ce, &Bs[w*2048 + i*512]);
    }
    __syncthreads();
#pragma unroll
    for (int kc = 0; kc < 2; kc++){
      v8s af[4], bf[4];
#pragma unroll
      for (int i = 0; i < 4; i++){
        int r = wr*64 + i*16 + mm;
        af[i] = *(const v8s*)&As[r*64 + (((kc*4 + g) ^ (r & 7)) * 8)];
      }
#pragma unroll
      for (int j = 0; j < 4; j++){
        int r = wc*64 + j*16 + mm;
        bf[j] = *(const v8s*)&Bs[r*64 + (((kc*4 + g) ^ (r & 7)) * 8)];
      }
#pragma unroll
      for (int i = 0; i < 4; i++)
#pragma unroll
        for (int j = 0; j < 4; j++)
          acc[i][j] = __builtin_amdgcn_mfma_f32_16x16x32_bf16(af[i], bf[j], acc[i][j], 0, 0, 0);
    }
  }
  if (OUT_BF16){
    u16* C = (u16*)Cv;
#pragma unroll
    for (int i = 0; i < 4; i++)
#pragma unroll
      for (int j = 0; j < 4; j++)
#pragma unroll
        for (int r = 0; r < 4; r++)
          C[(size_t)(m0 + wr*64 + i*16 + g*4 + r) * N + n0 + wc*64 + j*16 + mm] = f2b(acc[i][j][r]);
  } else {
    float* C = (float*)Cv;
#pragma unroll
    for (int i = 0; i < 4; i++)
#pragma unroll
      for (int j = 0; j < 4; j++)
#pragma unroll
        for (int r = 0; r < 4; r++)
          C[(size_t)(m0 + wr*64 + i*16 + g*4 + r) * N + n0 + wc*64 + j*16 + mm] = acc[i][j][r];
  }
}

// rope for Q (blocks 0..8191) and K (8192..10239) in one launch; bf16 in/out
__global__ __launch_bounds__(256) void rope_all(const u16* __restrict__ QKVb,
    const float* __restrict__ cosb, const float* __restrict__ sinb,
    u16* __restrict__ Qbf, u16* __restrict__ Kbf)
{
  int b = blockIdx.x;
  int d, h, s;
  const u16* src; u16* dst;
  if (b < 8192){
    int idx = b * 256 + threadIdx.x;
    d = idx & 31; h = (idx >> 5) & 31; s = idx >> 10;
    src = QKVb + (size_t)s * 3072 + h * HD + d;
    dst = Qbf + ((size_t)h * S_LEN + s) * HD + d;
  } else {
    int idx = (b - 8192) * 256 + threadIdx.x;
    d = idx & 31; h = (idx >> 5) & 7; s = idx >> 8;
    src = QKVb + (size_t)s * 3072 + 2048 + h * HD + d;
    dst = Kbf + ((size_t)h * S_LEN + s) * HD + d;
  }
  float c1 = cosb[s * HD + d],      s1 = sinb[s * HD + d];
  float c2 = cosb[s * HD + d + 32], s2 = sinb[s * HD + d + 32];
  float x1 = b2f(src[0]), x2 = b2f(src[32]);
  dst[0]  = f2b(x1 * c1 - x2 * s1);
  dst[32] = f2b(x2 * c2 + x1 * s2);
}

// V bf16 rows (stride u16 elems, head h at col h*64) -> Vt bf16 (8, 64, S)
__global__ __launch_bounds__(256) void vtrans(const u16* __restrict__ Vb, int stride, u16* __restrict__ Vt)
{
  __shared__ u16 T[64][72];
  const int b = blockIdx.x;
  const int h = b >> 5;
  const int s0 = (b & 31) * 64;
  const int t = threadIdx.x;
#pragma unroll
  for (int i = 0; i < 4; i++){
    int u = t + i * 256;
    int r = u >> 4, c4 = (u & 15) * 4;
    uint2 v = *(const uint2*)&Vb[(size_t)(s0 + r) * stride + h * HD + c4];
    T[c4+0][r] = (u16)(v.x & 0xffff); T[c4+1][r] = (u16)(v.x >> 16);
    T[c4+2][r] = (u16)(v.y & 0xffff); T[c4+3][r] = (u16)(v.y >> 16);
  }
  __syncthreads();
#pragma unroll
  for (int i = 0; i < 2; i++){
    int u = t + i * 256;
    int d = u >> 3, ch = (u & 7) * 8;
    *(uint4*)&Vt[((size_t)h * HD + d) * S_LEN + s0 + ch] = *(const uint4*)&T[d][ch];
  }
}

// Fused differential flash attention, 8 waves/block (Round-5 proven structure:
// grid (16,16), seg loop over q-tiles 31-p then p, uniform 33 iters/block).
// Round-7 change: k-loop unrolled by PAIRS of k-tiles with 4-deep K/V LDS
// buffers. One vmcnt(0)+s_barrier per PAIR (33 -> ~17 barriers), and the two
// tiles of a pair are independent chains (separate S regs, separate buffers)
// so tile B's QK MFMAs overlap tile A's exp/P-roundtrip stalls within each
// wave. P reuses one LDS region per head: in-wave DS FIFO orders A's pa-reads
// before B's P-writes. Tile order unchanged (ascending) -> identical FP sums.
// Epilogue: head-b waves deposit Ob*lam/lb into fp32 OLDS (overlays dead K
// bufs), head-a waves do diff + RMS + scale and write bf16 Ctx.
__global__ __launch_bounds__(512) void attn_fused(
    const u16* __restrict__ Qbf, const u16* __restrict__ Kbf, const u16* __restrict__ Vt,
    const float* __restrict__ lq1, const float* __restrict__ lk1,
    const float* __restrict__ lq2, const float* __restrict__ lk2,
    u16* __restrict__ Ctx)
{
  __shared__ __attribute__((aligned(16))) u16 SM[74752];   // 149504 B
  u16* QPa = SM;                  // 64 x 72 (Q then P, head a)
  u16* QPb = SM + 4608;           // 64 x 72 (head b)
  u16* Ksf = SM + 9216;           // [head:2][stage:4][64][64] u16 (64 KiB)
  u16* Vs  = SM + 41984;          // [stage:4][128][64] u16 (64 KiB)
  float* OLDS = (float*)(SM + 9216);  // 64 x 128 fp32 (32 KiB), overlays K bufs

  const int p   = blockIdx.x;                 // 0..15
  const int hp  = blockIdx.y;                 // 0..15
  const int kva = hp >> 2, kvb = kva + 4;
  const int t   = threadIdx.x, w = t >> 6, lane = t & 63;
  const int hb  = w >> 2;                     // 0 = head a, 1 = head b
  const int wq  = w & 3;                      // q-row group
  const int mm  = lane & 15, g = lane >> 4, g8 = g * 8;
  const int sr  = t >> 3;                     // staging row 0..63
  const int sc  = t & 7;
  const int so  = sc * 8;
  const int x0  = ((g ^ (mm & 7)) * 8);
  const int x1  = (((g + 4) ^ (mm & 7)) * 8);
  const int ce  = ((sc ^ (sr & 7)) * 8);      // XOR chunk swizzle for staging

  u16* QP = hb ? QPb : QPa;

  float lp1 = lq1[lane] * lk1[lane];
  float lp2 = lq2[lane] * lk2[lane];
#pragma unroll
  for (int off = 1; off < 64; off <<= 1){
    lp1 += __shfl_xor(lp1, off);
    lp2 += __shfl_xor(lp2, off);
  }
  const float lam = __expf(lp1) - __expf(lp2) + LAMBDA_INIT;

// stage K/V tile kk into LDS buffer (kk/64)&3
#define TILE_ISSUE(kk) do { \
    const int tb_ = ((kk) >> 6) & 3; \
    gld16(Vt  + ((size_t)kva * HD + sr) * S_LEN + (kk) + ce, Vs + tb_*8192 + (w*8)*64); \
    gld16(Vt  + ((size_t)kvb * HD + sr) * S_LEN + (kk) + ce, Vs + tb_*8192 + (w*8 + 64)*64); \
    gld16(Kbf + ((size_t)kva * S_LEN + (kk) + sr) * HD + ce, Ksf + tb_*4096 + (w*8)*64); \
    gld16(Kbf + ((size_t)kvb * S_LEN + (kk) + sr) * HD + ce, Ksf + 16384 + tb_*4096 + (w*8)*64); \
  } while(0)

// QK -> softmax -> PV for tile kk (buffer (kk/64)&3); dgf = diagonal masking
#define TILE_COMPUTE(kk, dgf) do { \
    const int tb_ = ((kk) >> 6) & 3; \
    const u16* Kh_ = Ksf + hb*16384 + tb_*4096; \
    v4f S_[4]; \
    _Pragma("unroll") \
    for (int n = 0; n < 4; n++){ \
      int row = n*16 + mm; \
      v8s kb0 = *(const v8s*)&Kh_[row*64 + x0]; \
      v8s kb1 = *(const v8s*)&Kh_[row*64 + x1]; \
      v4f z = (v4f){0.f,0.f,0.f,0.f}; \
      z = __builtin_amdgcn_mfma_f32_16x16x32_bf16(qa0, kb0, z, 0, 0, 0); \
      z = __builtin_amdgcn_mfma_f32_16x16x32_bf16(qa1, kb1, z, 0, 0, 0); \
      S_[n] = z; \
    } \
    _Pragma("unroll") \
    for (int n = 0; n < 4; n++) \
      _Pragma("unroll") \
      for (int r = 0; r < 4; r++){ \
        float pe = __expf(S_[n][r] * 0.125f); \
        if ((dgf) && (n*16 + mm > wq*16 + g*4 + r)) pe = 0.f; \
        l[r] += pe; \
        QP[(wq*16 + g*4 + r)*72 + n*16 + mm] = f2b(pe); \
      } \
    v8s pa0 = *(const v8s*)&QP[(wq*16 + mm)*72 + g8]; \
    v8s pa1 = *(const v8s*)&QP[(wq*16 + mm)*72 + 32 + g8]; \
    const u16* Vh_ = Vs + tb_*8192; \
    _Pragma("unroll") \
    for (int n = 0; n < 8; n++){ \
      int row = n*16 + mm; \
      v8s vb0 = *(const v8s*)&Vh_[row*64 + x0]; \
      v8s vb1 = *(const v8s*)&Vh_[row*64 + x1]; \
      O[n] = __builtin_amdgcn_mfma_f32_16x16x32_bf16(pa0, vb0, O[n], 0, 0, 0); \
      O[n] = __builtin_amdgcn_mfma_f32_16x16x32_bf16(pa1, vb1, O[n], 0, 0, 0); \
    } \
  } while(0)

  for (int seg = 0; seg < 2; seg++){
    const int qt = seg ? p : (31 - p);
    const int q0 = qt * 64;

    __syncthreads();   // prior segment fully done (incl. OLDS reads) before restage
    // issue tiles 0 and 1 into buffers 0,1; stage Q with plain stores
    TILE_ISSUE(0);
    if (64 <= q0) TILE_ISSUE(64);
    *(uint4*)&QPa[sr*72 + so] = *(const uint4*)&Qbf[((size_t)hp        * S_LEN + q0 + sr) * HD + so];
    *(uint4*)&QPb[sr*72 + so] = *(const uint4*)&Qbf[((size_t)(hp + 16) * S_LEN + q0 + sr) * HD + so];
    __syncthreads();   // Q visible, tiles 0(,1) drained
    v8s qa0 = *(const v8s*)&QP[(wq*16 + mm)*72 + g8];
    v8s qa1 = *(const v8s*)&QP[(wq*16 + mm)*72 + 32 + g8];

    v4f O[8];
#pragma unroll
    for (int n = 0; n < 8; n++) O[n] = (v4f){0.f,0.f,0.f,0.f};
    float l[4] = {0.f,0.f,0.f,0.f};

    int k0 = 0;
    for (; k0 + 64 <= q0; k0 += 128){
      if (k0){
        asm volatile("s_waitcnt vmcnt(0)" ::: "memory");
        __builtin_amdgcn_s_barrier();
        __builtin_amdgcn_sched_barrier(0);
      }
      // prefetch the NEXT pair into buffers (t+2)&3, (t+3)&3; in flight
      // across this whole pair (drained at next pair's top).
      if (k0 + 128 <= q0) TILE_ISSUE(k0 + 128);
      if (k0 + 192 <= q0) TILE_ISSUE(k0 + 192);
      TILE_COMPUTE(k0, false);
      TILE_COMPUTE(k0 + 64, (k0 + 64 == q0));
    }
    if (k0 <= q0){   // odd tile count: final single tile (always the diagonal)
      if (k0){
        asm volatile("s_waitcnt vmcnt(0)" ::: "memory");
        __builtin_amdgcn_s_barrier();
        __builtin_amdgcn_sched_barrier(0);
      }
      TILE_COMPUTE(k0, true);
    }

    // ---- epilogue for this segment ----
#pragma unroll
    for (int off = 1; off < 16; off <<= 1)
#pragma unroll
      for (int r = 0; r < 4; r++)
        l[r] += __shfl_xor(l[r], off);
    float il[4];
#pragma unroll
    for (int r = 0; r < 4; r++) il[r] = hb ? (lam / l[r]) : (1.0f / l[r]);

    __syncthreads();   // all QK/PV reads of Ks done; OLDS may overwrite K bufs
    if (hb){
#pragma unroll
      for (int n = 0; n < 8; n++)
#pragma unroll
        for (int r = 0; r < 4; r++)
          OLDS[(wq*16 + g*4 + r)*128 + n*16 + mm] = O[n][r] * il[r];
    }
    __syncthreads();
    if (!hb){
      float av[8][4];
      float ss[4] = {0.f,0.f,0.f,0.f};
#pragma unroll
      for (int n = 0; n < 8; n++)
#pragma unroll
        for (int r = 0; r < 4; r++){
          float a = O[n][r] * il[r] - OLDS[(wq*16 + g*4 + r)*128 + n*16 + mm];
          av[n][r] = a;
          ss[r] += a * a;
        }
#pragma unroll
      for (int off = 1; off < 16; off <<= 1)
#pragma unroll
        for (int r = 0; r < 4; r++)
          ss[r] += __shfl_xor(ss[r], off);
      float rv[4];
#pragma unroll
      for (int r = 0; r < 4; r++)
        rv[r] = rsqrtf(ss[r] * (1.0f/128.0f) + 1e-6f) * ONE_MINUS_LI;
#pragma unroll
      for (int n = 0; n < 8; n++)
#pragma unroll
        for (int r = 0; r < 4; r++){
          int srow = q0 + wq*16 + g*4 + r;
          Ctx[(size_t)srow * HID + hp * DVV + n*16 + mm] = f2b(av[n][r] * rv[r]);
        }
    }
  }
#undef TILE_ISSUE
#undef TILE_COMPUTE
}

extern "C" void kernel_launch(void* const* d_in, const int* in_sizes, int n_in,
                              void* d_out, int out_size, void* d_ws, size_t ws_size,
                              hipStream_t stream)
{
  (void)in_sizes; (void)n_in; (void)out_size; (void)ws_size;
  const float* hs   = (const float*)d_in[0];
  const float* cosb = (const float*)d_in[1];
  const float* sinb = (const float*)d_in[2];
  const float* Wq   = (const float*)d_in[3];
  const float* Wk   = (const float*)d_in[4];
  const float* Wv   = (const float*)d_in[5];
  const float* Wo   = (const float*)d_in[6];
  const float* lq1  = (const float*)d_in[7];
  const float* lk1  = (const float*)d_in[8];
  const float* lq2  = (const float*)d_in[9];
  const float* lk2  = (const float*)d_in[10];

  char* ws = (char*)d_ws;
  u16* hsb   = (u16*)(ws);                   // [0,8) MB bf16 hs
  u16* Wqkvb = (u16*)(ws + (8u  << 20));     // [8,20) bf16 [Wq;Wk;Wv] 3072x2048
  u16* QKVb  = (u16*)(ws + (20u << 20));     // [20,32) bf16 (S,3072)
  u16* Ctx   = (u16*)(ws + (20u << 20));     // [20,28) overlays QKVb after rope/vtrans
  u16* Wob   = (u16*)(ws + (32u << 20));     // [32,40) bf16 Wo
  u16* Kbf   = (u16*)(ws + (44u << 20));     // [44,46) bf16 (8,S,64)
  u16* Vt    = (u16*)(ws + (46u << 20));     // [46,48) bf16 (8,64,S)
  u16* Qbf   = (u16*)(ws + (48u << 20));     // [48,56) bf16 (32,S,64)

  cast5<<<7168, 256, 0, stream>>>(hs, Wq, Wk, Wv, Wo, hsb, Wqkvb, Wob);
  gemm_bf16<1><<<dim3(24, 16), 256, 0, stream>>>(hsb, Wqkvb, QKVb, S_LEN, 3072, HID);
  rope_all<<<10240, 256, 0, stream>>>(QKVb, cosb, sinb, Qbf, Kbf);
  vtrans<<<NKV * (S_LEN/64), 256, 0, stream>>>(QKVb + 2560, 3072, Vt);
  attn_fused<<<dim3(16, 16), 512, 0, stream>>>(Qbf, Kbf, Vt, lq1, lk1, lq2, lk2, Ctx);
  gemm_bf16<0><<<dim3(16, 16), 256, 0, stream>>>(Ctx, Wob, (float*)d_out, S_LEN, 2048, HID);
}

// Round 8
// 245.022 us; speedup vs baseline: 1.1072x; 1.0265x over previous
//
#include <hip/hip_runtime.h>

typedef unsigned short u16;
typedef __attribute__((ext_vector_type(8))) short v8s;
typedef __attribute__((ext_vector_type(4))) float v4f;

#define S_LEN 2048
#define HID   2048
#define NH    32
#define NKV   8
#define HD    64
#define DVV   128
#define LAMBDA_INIT  0.7455692280263525f
#define ONE_MINUS_LI 0.2544307719736475f

__device__ __forceinline__ u16 f2b(float f){
  union { float f; unsigned int i; } v; v.f = f;
  unsigned int x = v.i;
  unsigned int r = (x + 0x7fffu + ((x >> 16) & 1u)) >> 16;
  return (u16)r;
}
__device__ __forceinline__ float b2f(u16 u){
  union { unsigned int i; float f; } v; v.i = ((unsigned int)u) << 16; return v.f;
}

__device__ __forceinline__ void gld16(const u16* g, u16* l){
  __builtin_amdgcn_global_load_lds(
      (const __attribute__((address_space(1))) unsigned int*)g,
      (__attribute__((address_space(3))) unsigned int*)l, 16, 0, 0);
}

// one launch casting hs, Wq, Wk, Wv, Wo to bf16 (regions by blockIdx)
__global__ __launch_bounds__(256) void cast5(
    const float* __restrict__ hs, const float* __restrict__ Wq,
    const float* __restrict__ Wk, const float* __restrict__ Wv,
    const float* __restrict__ Wo,
    u16* __restrict__ hsb, u16* __restrict__ Wqkvb, u16* __restrict__ Wob)
{
  int b = blockIdx.x;
  const float* S; u16* D; int rb;
  if (b < 2048)      { S = hs; D = hsb;             rb = b; }
  else if (b < 4096) { S = Wq; D = Wqkvb;           rb = b - 2048; }
  else if (b < 4608) { S = Wk; D = Wqkvb + 4194304; rb = b - 4096; }
  else if (b < 5120) { S = Wv; D = Wqkvb + 5242880; rb = b - 4608; }
  else               { S = Wo; D = Wob;             rb = b - 5120; }
  size_t i = ((size_t)rb * 256 + threadIdx.x) * 8;
  float4 a = *(const float4*)(S + i);
  float4 c = *(const float4*)(S + i + 4);
  u16 o[8] = {f2b(a.x), f2b(a.y), f2b(a.z), f2b(a.w), f2b(c.x), f2b(c.y), f2b(c.z), f2b(c.w)};
  *(uint4*)(D + i) = *(const uint4*)o;
}

// C[m][n] = sum_k A[m*K+k]*B[n*K+k]; A,B bf16; C fp32 or bf16. 128x128 tile, BK=64,
// global_load_lds staging with XOR chunk swizzle (row&7).
// Round-8: DOUBLE-BUFFERED LDS. Stage tile k+1 during compute of tile k; one
// raw vmcnt(0)+s_barrier per K-step (was 2 barriers with a zero-slack drain).
// At these shapes (256-384 blocks = 1-1.5 blocks/CU) there is no co-resident
// partner to hide the drain, so the explicit pipeline matters (same mechanism
// that took attn 69->59.4 in R5).
template<int OUT_BF16>
__global__ __launch_bounds__(256) void gemm_bf16(const u16* __restrict__ A, const u16* __restrict__ B,
                                                 void* __restrict__ Cv, int M, int N, int K)
{
  __shared__ __attribute__((aligned(16))) u16 As[2][128*64];
  __shared__ __attribute__((aligned(16))) u16 Bs[2][128*64];
  const int t    = threadIdx.x;
  const int w    = t >> 6, lane = t & 63;
  const int mm   = lane & 15, g = lane >> 4;
  const int wr   = w >> 1, wc = w & 1;
  const int m0   = blockIdx.y * 128, n0 = blockIdx.x * 128;
  const int srow = w*32 + (lane >> 3);
  const int sch  = lane & 7;

  v4f acc[4][4];
#pragma unroll
  for (int i = 0; i < 4; i++)
#pragma unroll
    for (int j = 0; j < 4; j++) acc[i][j] = (v4f){0.f,0.f,0.f,0.f};

#define G_STAGE(kk, buf) do { \
    _Pragma("unroll") \
    for (int i = 0; i < 4; i++){ \
      int r  = srow + i*8; \
      int ce = ((sch ^ (r & 7)) * 8); \
      gld16(A + (size_t)(m0 + r) * K + (kk) + ce, &As[buf][w*2048 + i*512]); \
      gld16(B + (size_t)(n0 + r) * K + (kk) + ce, &Bs[buf][w*2048 + i*512]); \
    } \
  } while(0)

  // prologue: stage tile 0 into buffer 0, full drain
  G_STAGE(0, 0);
  __syncthreads();

  for (int k0 = 0; k0 < K; k0 += 64){
    const int cur = (k0 >> 6) & 1;
    if (k0){
      // tile k0 was staged one full iteration ago: drain (~0 stall) + sync
      asm volatile("s_waitcnt vmcnt(0)" ::: "memory");
      __builtin_amdgcn_s_barrier();
      __builtin_amdgcn_sched_barrier(0);
    }
    // prefetch tile k0+64 into the other buffer; stays in flight all iter.
    // (write-after-read safe: buf cur^1 was last read in iter k0-64, and all
    // waves passed this iter's barrier after that compute.)
    if (k0 + 64 < K) G_STAGE(k0 + 64, cur ^ 1);

#pragma unroll
    for (int kc = 0; kc < 2; kc++){
      v8s af[4], bf[4];
#pragma unroll
      for (int i = 0; i < 4; i++){
        int r = wr*64 + i*16 + mm;
        af[i] = *(const v8s*)&As[cur][r*64 + (((kc*4 + g) ^ (r & 7)) * 8)];
      }
#pragma unroll
      for (int j = 0; j < 4; j++){
        int r = wc*64 + j*16 + mm;
        bf[j] = *(const v8s*)&Bs[cur][r*64 + (((kc*4 + g) ^ (r & 7)) * 8)];
      }
#pragma unroll
      for (int i = 0; i < 4; i++)
#pragma unroll
        for (int j = 0; j < 4; j++)
          acc[i][j] = __builtin_amdgcn_mfma_f32_16x16x32_bf16(af[i], bf[j], acc[i][j], 0, 0, 0);
    }
  }
#undef G_STAGE

  if (OUT_BF16){
    u16* C = (u16*)Cv;
#pragma unroll
    for (int i = 0; i < 4; i++)
#pragma unroll
      for (int j = 0; j < 4; j++)
#pragma unroll
        for (int r = 0; r < 4; r++)
          C[(size_t)(m0 + wr*64 + i*16 + g*4 + r) * N + n0 + wc*64 + j*16 + mm] = f2b(acc[i][j][r]);
  } else {
    float* C = (float*)Cv;
#pragma unroll
    for (int i = 0; i < 4; i++)
#pragma unroll
      for (int j = 0; j < 4; j++)
#pragma unroll
        for (int r = 0; r < 4; r++)
          C[(size_t)(m0 + wr*64 + i*16 + g*4 + r) * N + n0 + wc*64 + j*16 + mm] = acc[i][j][r];
  }
}

// rope for Q (blocks 0..8191) and K (8192..10239) in one launch; bf16 in/out
__global__ __launch_bounds__(256) void rope_all(const u16* __restrict__ QKVb,
    const float* __restrict__ cosb, const float* __restrict__ sinb,
    u16* __restrict__ Qbf, u16* __restrict__ Kbf)
{
  int b = blockIdx.x;
  int d, h, s;
  const u16* src; u16* dst;
  if (b < 8192){
    int idx = b * 256 + threadIdx.x;
    d = idx & 31; h = (idx >> 5) & 31; s = idx >> 10;
    src = QKVb + (size_t)s * 3072 + h * HD + d;
    dst = Qbf + ((size_t)h * S_LEN + s) * HD + d;
  } else {
    int idx = (b - 8192) * 256 + threadIdx.x;
    d = idx & 31; h = (idx >> 5) & 7; s = idx >> 8;
    src = QKVb + (size_t)s * 3072 + 2048 + h * HD + d;
    dst = Kbf + ((size_t)h * S_LEN + s) * HD + d;
  }
  float c1 = cosb[s * HD + d],      s1 = sinb[s * HD + d];
  float c2 = cosb[s * HD + d + 32], s2 = sinb[s * HD + d + 32];
  float x1 = b2f(src[0]), x2 = b2f(src[32]);
  dst[0]  = f2b(x1 * c1 - x2 * s1);
  dst[32] = f2b(x2 * c2 + x1 * s2);
}

// V bf16 rows (stride u16 elems, head h at col h*64) -> Vt bf16 (8, 64, S)
__global__ __launch_bounds__(256) void vtrans(const u16* __restrict__ Vb, int stride, u16* __restrict__ Vt)
{
  __shared__ u16 T[64][72];
  const int b = blockIdx.x;
  const int h = b >> 5;
  const int s0 = (b & 31) * 64;
  const int t = threadIdx.x;
#pragma unroll
  for (int i = 0; i < 4; i++){
    int u = t + i * 256;
    int r = u >> 4, c4 = (u & 15) * 4;
    uint2 v = *(const uint2*)&Vb[(size_t)(s0 + r) * stride + h * HD + c4];
    T[c4+0][r] = (u16)(v.x & 0xffff); T[c4+1][r] = (u16)(v.x >> 16);
    T[c4+2][r] = (u16)(v.y & 0xffff); T[c4+3][r] = (u16)(v.y >> 16);
  }
  __syncthreads();
#pragma unroll
  for (int i = 0; i < 2; i++){
    int u = t + i * 256;
    int d = u >> 3, ch = (u & 7) * 8;
    *(uint4*)&Vt[((size_t)h * HD + d) * S_LEN + s0 + ch] = *(const uint4*)&T[d][ch];
  }
}

// Fused differential flash attention, 8 waves/block — exact Round-5 structure
// (grid (16,16), seg loop 31-p then p, V double-buffered + staged one full
// iteration ahead, no mid-iteration barrier, raw vmcnt(0)+s_barrier per iter)
// + T5: s_setprio(1) around the QK and PV MFMA clusters (waves drift freely
// within an iteration, so the CU scheduler can favor MFMA-phase waves).
__global__ __launch_bounds__(512) void attn_fused(
    const u16* __restrict__ Qbf, const u16* __restrict__ Kbf, const u16* __restrict__ Vt,
    const float* __restrict__ lq1, const float* __restrict__ lk1,
    const float* __restrict__ lq2, const float* __restrict__ lk2,
    u16* __restrict__ Ctx)
{
  __shared__ __attribute__((aligned(16))) u16 SM[41984];   // 83968 B
  u16* QPa = SM;                 // 64 x 72 (Q then P, head a)
  u16* QPb = SM + 4608;          // 64 x 72 (head b)
  u16* Ksf = SM + 9216;          // Ksa[2] (2x 64x64) then Ksb[2]
  u16* Vs  = SM + 25600;         // V dbuf: 2 x (128 x 64)
  float* OLDS = (float*)(SM + 9216);  // 64 x 128 fp32, overlays K bufs (epilogue only)

  const int p   = blockIdx.x;                 // 0..15
  const int hp  = blockIdx.y;                 // 0..15
  const int kva = hp >> 2, kvb = kva + 4;
  const int t   = threadIdx.x, w = t >> 6, lane = t & 63;
  const int hb  = w >> 2;                     // 0 = head a, 1 = head b
  const int wq  = w & 3;                      // q-row group
  const int mm  = lane & 15, g = lane >> 4, g8 = g * 8;
  const int sr  = t >> 3;                     // staging row 0..63
  const int sc  = t & 7;
  const int so  = sc * 8;
  const int x0  = ((g ^ (mm & 7)) * 8);
  const int x1  = (((g + 4) ^ (mm & 7)) * 8);

  u16* QP = hb ? QPb : QPa;

  float lp1 = lq1[lane] * lk1[lane];
  float lp2 = lq2[lane] * lk2[lane];
#pragma unroll
  for (int off = 1; off < 64; off <<= 1){
    lp1 += __shfl_xor(lp1, off);
    lp2 += __shfl_xor(lp2, off);
  }
  const float lam = __expf(lp1) - __expf(lp2) + LAMBDA_INIT;

  for (int seg = 0; seg < 2; seg++){
    const int qt = seg ? p : (31 - p);
    const int q0 = qt * 64;

    __syncthreads();   // prior segment fully done (incl. OLDS reads) before restage
    // issue K(0) and V(0) into buffer 0; stage Q tiles with plain stores
    {
      int ce = ((sc ^ (sr & 7)) * 8);
      gld16(Kbf + ((size_t)kva * S_LEN + sr) * HD + ce, Ksf + (w*8)*64);
      gld16(Kbf + ((size_t)kvb * S_LEN + sr) * HD + ce, Ksf + 8192 + (w*8)*64);
      gld16(Vt + ((size_t)kva * HD + sr) * S_LEN + ce, Vs + (w*8)*64);
      gld16(Vt + ((size_t)kvb * HD + sr) * S_LEN + ce, Vs + (w*8 + 64)*64);
    }
    *(uint4*)&QPa[sr*72 + so] = *(const uint4*)&Qbf[((size_t)hp        * S_LEN + q0 + sr) * HD + so];
    *(uint4*)&QPb[sr*72 + so] = *(const uint4*)&Qbf[((size_t)(hp + 16) * S_LEN + q0 + sr) * HD + so];
    __syncthreads();   // Q visible, K(0)/V(0) drained (full barrier drains vmcnt)
    v8s qa0 = *(const v8s*)&QP[(wq*16 + mm)*72 + g8];
    v8s qa1 = *(const v8s*)&QP[(wq*16 + mm)*72 + 32 + g8];

    v4f O[8];
#pragma unroll
    for (int n = 0; n < 8; n++) O[n] = (v4f){0.f,0.f,0.f,0.f};
    float l[4] = {0.f,0.f,0.f,0.f};

    for (int k0 = 0; k0 <= q0; k0 += 64){
      const int cur = (k0 >> 6) & 1;
      if (k0){
        // K(k0),V(k0) issued one full iteration ago: drain (≈0 stall), sync.
        asm volatile("s_waitcnt vmcnt(0)" ::: "memory");
        __builtin_amdgcn_s_barrier();
        __builtin_amdgcn_sched_barrier(0);
      }
      // prefetch K(k0+64), V(k0+64) into the other buffers; in flight all iter
      if (k0 + 64 <= q0){
        int ce = ((sc ^ (sr & 7)) * 8);
        gld16(Vt + ((size_t)kva * HD + sr) * S_LEN + k0 + 64 + ce, Vs + (cur^1)*8192 + (w*8)*64);
        gld16(Vt + ((size_t)kvb * HD + sr) * S_LEN + k0 + 64 + ce, Vs + (cur^1)*8192 + (w*8 + 64)*64);
        gld16(Kbf + ((size_t)kva * S_LEN + k0 + 64 + sr) * HD + ce, Ksf + (cur^1)*4096 + (w*8)*64);
        gld16(Kbf + ((size_t)kvb * S_LEN + k0 + 64 + sr) * HD + ce, Ksf + 8192 + (cur^1)*4096 + (w*8)*64);
      }

      const u16* Kh = Ksf + hb*8192 + cur*4096;
      const bool dg = (k0 == q0);
      v4f S[4];
      __builtin_amdgcn_s_setprio(1);
#pragma unroll
      for (int n = 0; n < 4; n++){
        int row = n*16 + mm;
        v8s kb0 = *(const v8s*)&Kh[row*64 + x0];
        v8s kb1 = *(const v8s*)&Kh[row*64 + x1];
        v4f z = (v4f){0.f,0.f,0.f,0.f};
        z = __builtin_amdgcn_mfma_f32_16x16x32_bf16(qa0, kb0, z, 0, 0, 0);
        z = __builtin_amdgcn_mfma_f32_16x16x32_bf16(qa1, kb1, z, 0, 0, 0);
        S[n] = z;
      }
      __builtin_amdgcn_s_setprio(0);
      // P is wave-private (rows wq*16..wq*16+15): no barrier around store/reload
#pragma unroll
      for (int n = 0; n < 4; n++)
#pragma unroll
        for (int r = 0; r < 4; r++){
          float pe = __expf(S[n][r] * 0.125f);
          if (dg && (n*16 + mm > wq*16 + g*4 + r)) pe = 0.f;
          l[r] += pe;
          QP[(wq*16 + g*4 + r)*72 + n*16 + mm] = f2b(pe);
        }
      v8s pa0 = *(const v8s*)&QP[(wq*16 + mm)*72 + g8];
      v8s pa1 = *(const v8s*)&QP[(wq*16 + mm)*72 + 32 + g8];
      const u16* Vh = Vs + cur*8192;
      __builtin_amdgcn_s_setprio(1);
#pragma unroll
      for (int n = 0; n < 8; n++){
        int row = n*16 + mm;
        v8s vb0 = *(const v8s*)&Vh[row*64 + x0];
        v8s vb1 = *(const v8s*)&Vh[row*64 + x1];
        O[n] = __builtin_amdgcn_mfma_f32_16x16x32_bf16(pa0, vb0, O[n], 0, 0, 0);
        O[n] = __builtin_amdgcn_mfma_f32_16x16x32_bf16(pa1, vb1, O[n], 0, 0, 0);
      }
      __builtin_amdgcn_s_setprio(0);
    }

    // ---- epilogue for this segment ----
#pragma unroll
    for (int off = 1; off < 16; off <<= 1)
#pragma unroll
      for (int r = 0; r < 4; r++)
        l[r] += __shfl_xor(l[r], off);
    float il[4];
#pragma unroll
    for (int r = 0; r < 4; r++) il[r] = hb ? (lam / l[r]) : (1.0f / l[r]);

    __syncthreads();   // all QK reads of Ks done; OLDS may overwrite K bufs
    if (hb){
#pragma unroll
      for (int n = 0; n < 8; n++)
#pragma unroll
        for (int r = 0; r < 4; r++)
          OLDS[(wq*16 + g*4 + r)*128 + n*16 + mm] = O[n][r] * il[r];
    }
    __syncthreads();
    if (!hb){
      float av[8][4];
      float ss[4] = {0.f,0.f,0.f,0.f};
#pragma unroll
      for (int n = 0; n < 8; n++)
#pragma unroll
        for (int r = 0; r < 4; r++){
          float a = O[n][r] * il[r] - OLDS[(wq*16 + g*4 + r)*128 + n*16 + mm];
          av[n][r] = a;
          ss[r] += a * a;
        }
#pragma unroll
      for (int off = 1; off < 16; off <<= 1)
#pragma unroll
        for (int r = 0; r < 4; r++)
          ss[r] += __shfl_xor(ss[r], off);
      float rv[4];
#pragma unroll
      for (int r = 0; r < 4; r++)
        rv[r] = rsqrtf(ss[r] * (1.0f/128.0f) + 1e-6f) * ONE_MINUS_LI;
#pragma unroll
      for (int n = 0; n < 8; n++)
#pragma unroll
        for (int r = 0; r < 4; r++){
          int srow = q0 + wq*16 + g*4 + r;
          Ctx[(size_t)srow * HID + hp * DVV + n*16 + mm] = f2b(av[n][r] * rv[r]);
        }
    }
  }
}

extern "C" void kernel_launch(void* const* d_in, const int* in_sizes, int n_in,
                              void* d_out, int out_size, void* d_ws, size_t ws_size,
                              hipStream_t stream)
{
  (void)in_sizes; (void)n_in; (void)out_size; (void)ws_size;
  const float* hs   = (const float*)d_in[0];
  const float* cosb = (const float*)d_in[1];
  const float* sinb = (const float*)d_in[2];
  const float* Wq   = (const float*)d_in[3];
  const float* Wk   = (const float*)d_in[4];
  const float* Wv   = (const float*)d_in[5];
  const float* Wo   = (const float*)d_in[6];
  const float* lq1  = (const float*)d_in[7];
  const float* lk1  = (const float*)d_in[8];
  const float* lq2  = (const float*)d_in[9];
  const float* lk2  = (const float*)d_in[10];

  char* ws = (char*)d_ws;
  u16* hsb   = (u16*)(ws);                   // [0,8) MB bf16 hs
  u16* Wqkvb = (u16*)(ws + (8u  << 20));     // [8,20) bf16 [Wq;Wk;Wv] 3072x2048
  u16* QKVb  = (u16*)(ws + (20u << 20));     // [20,32) bf16 (S,3072)
  u16* Ctx   = (u16*)(ws + (20u << 20));     // [20,28) overlays QKVb after rope/vtrans
  u16* Wob   = (u16*)(ws + (32u << 20));     // [32,40) bf16 Wo
  u16* Kbf   = (u16*)(ws + (44u << 20));     // [44,46) bf16 (8,S,64)
  u16* Vt    = (u16*)(ws + (46u << 20));     // [46,48) bf16 (8,64,S)
  u16* Qbf   = (u16*)(ws + (48u << 20));     // [48,56) bf16 (32,S,64)

  cast5<<<7168, 256, 0, stream>>>(hs, Wq, Wk, Wv, Wo, hsb, Wqkvb, Wob);
  gemm_bf16<1><<<dim3(24, 16), 256, 0, stream>>>(hsb, Wqkvb, QKVb, S_LEN, 3072, HID);
  rope_all<<<10240, 256, 0, stream>>>(QKVb, cosb, sinb, Qbf, Kbf);
  vtrans<<<NKV * (S_LEN/64), 256, 0, stream>>>(QKVb + 2560, 3072, Vt);
  attn_fused<<<dim3(16, 16), 512, 0, stream>>>(Qbf, Kbf, Vt, lq1, lk1, lq2, lk2, Ctx);
  gemm_bf16<0><<<dim3(16, 16), 256, 0, stream>>>(Ctx, Wob, (float*)d_out, S_LEN, 2048, HID);
}

// Round 9
// 231.698 us; speedup vs baseline: 1.1709x; 1.0575x over previous
//
#include <hip/hip_runtime.h>

typedef unsigned short u16;
typedef __attribute__((ext_vector_type(8))) short v8s;
typedef __attribute__((ext_vector_type(4))) float v4f;

#define S_LEN 2048
#define HID   2048
#define NH    32
#define NKV   8
#define HD    64
#define DVV   128
#define LAMBDA_INIT  0.7455692280263525f
#define ONE_MINUS_LI 0.2544307719736475f

__device__ __forceinline__ u16 f2b(float f){
  union { float f; unsigned int i; } v; v.f = f;
  unsigned int x = v.i;
  unsigned int r = (x + 0x7fffu + ((x >> 16) & 1u)) >> 16;
  return (u16)r;
}
__device__ __forceinline__ float b2f(u16 u){
  union { unsigned int i; float f; } v; v.i = ((unsigned int)u) << 16; return v.f;
}

__device__ __forceinline__ void gld16(const u16* g, u16* l){
  __builtin_amdgcn_global_load_lds(
      (const __attribute__((address_space(1))) unsigned int*)g,
      (__attribute__((address_space(3))) unsigned int*)l, 16, 0, 0);
}

// one launch casting hs, Wq, Wk, Wv, Wo to bf16 (regions by blockIdx)
__global__ __launch_bounds__(256) void cast5(
    const float* __restrict__ hs, const float* __restrict__ Wq,
    const float* __restrict__ Wk, const float* __restrict__ Wv,
    const float* __restrict__ Wo,
    u16* __restrict__ hsb, u16* __restrict__ Wqkvb, u16* __restrict__ Wob)
{
  int b = blockIdx.x;
  const float* S; u16* D; int rb;
  if (b < 2048)      { S = hs; D = hsb;             rb = b; }
  else if (b < 4096) { S = Wq; D = Wqkvb;           rb = b - 2048; }
  else if (b < 4608) { S = Wk; D = Wqkvb + 4194304; rb = b - 4096; }
  else if (b < 5120) { S = Wv; D = Wqkvb + 5242880; rb = b - 4608; }
  else               { S = Wo; D = Wob;             rb = b - 5120; }
  size_t i = ((size_t)rb * 256 + threadIdx.x) * 8;
  float4 a = *(const float4*)(S + i);
  float4 c = *(const float4*)(S + i + 4);
  u16 o[8] = {f2b(a.x), f2b(a.y), f2b(a.z), f2b(a.w), f2b(c.x), f2b(c.y), f2b(c.z), f2b(c.w)};
  *(uint4*)(D + i) = *(const uint4*)o;
}

// C[m][n] = sum_k A[m*K+k]*B[n*K+k]; A,B bf16; C fp32 or bf16.
// Round-9: 128x64 tile (BM=128, BN=64), BK=64, double-buffered LDS with the
// R8 pipeline (prefetch next tile during compute, one raw vmcnt(0)+s_barrier
// per K-step). Halving BN doubles/triples grid blocks: gemm<1> 768 blocks =
// 3 blocks/CU, gemm<0> 512 = 2/CU (LDS 48 KB dbuf -> 3 fit in 160 KB).
// Mechanism: m102 showed the SAME 128x128 structure jumps 320->912 TF going
// from 1 to 4 blocks/CU — co-resident blocks fill each other's drain/MFMA
// holes. Co-residency for this gemm is already HW-proven (R8 gemm<1> ran 2
// blocks/CU on 128 CUs and passed).
// Wave w computes rows w*32..w*32+31 x all 64 cols (acc 2x4 v4f = 32 VGPR).
template<int OUT_BF16>
__global__ __launch_bounds__(256) void gemm_bf16(const u16* __restrict__ A, const u16* __restrict__ B,
                                                 void* __restrict__ Cv, int M, int N, int K)
{
  __shared__ __attribute__((aligned(16))) u16 As[2][128*64];
  __shared__ __attribute__((aligned(16))) u16 Bs[2][64*64];
  const int t    = threadIdx.x;
  const int w    = t >> 6, lane = t & 63;
  const int mm   = lane & 15, g = lane >> 4;
  const int m0   = blockIdx.y * 128, n0 = blockIdx.x * 64;
  const int lr   = lane >> 3;      // 0..7
  const int sch  = lane & 7;

  v4f acc[2][4];
#pragma unroll
  for (int i = 0; i < 2; i++)
#pragma unroll
    for (int j = 0; j < 4; j++) acc[i][j] = (v4f){0.f,0.f,0.f,0.f};

#define G_STAGE(kk, buf) do { \
    _Pragma("unroll") \
    for (int i = 0; i < 4; i++){ \
      int r  = w*32 + lr + i*8; \
      int ce = ((sch ^ (r & 7)) * 8); \
      gld16(A + (size_t)(m0 + r) * K + (kk) + ce, &As[buf][w*2048 + i*512]); \
    } \
    _Pragma("unroll") \
    for (int i = 0; i < 2; i++){ \
      int r  = w*16 + lr + i*8; \
      int ce = ((sch ^ (r & 7)) * 8); \
      gld16(B + (size_t)(n0 + r) * K + (kk) + ce, &Bs[buf][w*1024 + i*512]); \
    } \
  } while(0)

  // prologue: stage tile 0 into buffer 0, full drain
  G_STAGE(0, 0);
  __syncthreads();

  for (int k0 = 0; k0 < K; k0 += 64){
    const int cur = (k0 >> 6) & 1;
    if (k0){
      // tile k0 was staged one full iteration ago: drain (~0 stall) + sync
      asm volatile("s_waitcnt vmcnt(0)" ::: "memory");
      __builtin_amdgcn_s_barrier();
      __builtin_amdgcn_sched_barrier(0);
    }
    if (k0 + 64 < K) G_STAGE(k0 + 64, cur ^ 1);

#pragma unroll
    for (int kc = 0; kc < 2; kc++){
      v8s af[2], bf[4];
#pragma unroll
      for (int i = 0; i < 2; i++){
        int r = w*32 + i*16 + mm;
        af[i] = *(const v8s*)&As[cur][r*64 + (((kc*4 + g) ^ (r & 7)) * 8)];
      }
#pragma unroll
      for (int j = 0; j < 4; j++){
        int r = j*16 + mm;
        bf[j] = *(const v8s*)&Bs[cur][r*64 + (((kc*4 + g) ^ (r & 7)) * 8)];
      }
#pragma unroll
      for (int i = 0; i < 2; i++)
#pragma unroll
        for (int j = 0; j < 4; j++)
          acc[i][j] = __builtin_amdgcn_mfma_f32_16x16x32_bf16(af[i], bf[j], acc[i][j], 0, 0, 0);
    }
  }
#undef G_STAGE

  if (OUT_BF16){
    u16* C = (u16*)Cv;
#pragma unroll
    for (int i = 0; i < 2; i++)
#pragma unroll
      for (int j = 0; j < 4; j++)
#pragma unroll
        for (int r = 0; r < 4; r++)
          C[(size_t)(m0 + w*32 + i*16 + g*4 + r) * N + n0 + j*16 + mm] = f2b(acc[i][j][r]);
  } else {
    float* C = (float*)Cv;
#pragma unroll
    for (int i = 0; i < 2; i++)
#pragma unroll
      for (int j = 0; j < 4; j++)
#pragma unroll
        for (int r = 0; r < 4; r++)
          C[(size_t)(m0 + w*32 + i*16 + g*4 + r) * N + n0 + j*16 + mm] = acc[i][j][r];
  }
}

// rope for Q (blocks 0..8191) and K (8192..10239) in one launch; bf16 in/out
__global__ __launch_bounds__(256) void rope_all(const u16* __restrict__ QKVb,
    const float* __restrict__ cosb, const float* __restrict__ sinb,
    u16* __restrict__ Qbf, u16* __restrict__ Kbf)
{
  int b = blockIdx.x;
  int d, h, s;
  const u16* src; u16* dst;
  if (b < 8192){
    int idx = b * 256 + threadIdx.x;
    d = idx & 31; h = (idx >> 5) & 31; s = idx >> 10;
    src = QKVb + (size_t)s * 3072 + h * HD + d;
    dst = Qbf + ((size_t)h * S_LEN + s) * HD + d;
  } else {
    int idx = (b - 8192) * 256 + threadIdx.x;
    d = idx & 31; h = (idx >> 5) & 7; s = idx >> 8;
    src = QKVb + (size_t)s * 3072 + 2048 + h * HD + d;
    dst = Kbf + ((size_t)h * S_LEN + s) * HD + d;
  }
  float c1 = cosb[s * HD + d],      s1 = sinb[s * HD + d];
  float c2 = cosb[s * HD + d + 32], s2 = sinb[s * HD + d + 32];
  float x1 = b2f(src[0]), x2 = b2f(src[32]);
  dst[0]  = f2b(x1 * c1 - x2 * s1);
  dst[32] = f2b(x2 * c2 + x1 * s2);
}

// V bf16 rows (stride u16 elems, head h at col h*64) -> Vt bf16 (8, 64, S)
__global__ __launch_bounds__(256) void vtrans(const u16* __restrict__ Vb, int stride, u16* __restrict__ Vt)
{
  __shared__ u16 T[64][72];
  const int b = blockIdx.x;
  const int h = b >> 5;
  const int s0 = (b & 31) * 64;
  const int t = threadIdx.x;
#pragma unroll
  for (int i = 0; i < 4; i++){
    int u = t + i * 256;
    int r = u >> 4, c4 = (u & 15) * 4;
    uint2 v = *(const uint2*)&Vb[(size_t)(s0 + r) * stride + h * HD + c4];
    T[c4+0][r] = (u16)(v.x & 0xffff); T[c4+1][r] = (u16)(v.x >> 16);
    T[c4+2][r] = (u16)(v.y & 0xffff); T[c4+3][r] = (u16)(v.y >> 16);
  }
  __syncthreads();
#pragma unroll
  for (int i = 0; i < 2; i++){
    int u = t + i * 256;
    int d = u >> 3, ch = (u & 7) * 8;
    *(uint4*)&Vt[((size_t)h * HD + d) * S_LEN + s0 + ch] = *(const uint4*)&T[d][ch];
  }
}

// Fused differential flash attention, 8 waves/block — Round-8 structure
// (grid (16,16), seg loop 31-p then p, V double-buffered + staged one full
// iteration ahead, no mid-iteration barrier, raw vmcnt(0)+s_barrier per iter,
// setprio around MFMA clusters).
__global__ __launch_bounds__(512) void attn_fused(
    const u16* __restrict__ Qbf, const u16* __restrict__ Kbf, const u16* __restrict__ Vt,
    const float* __restrict__ lq1, const float* __restrict__ lk1,
    const float* __restrict__ lq2, const float* __restrict__ lk2,
    u16* __restrict__ Ctx)
{
  __shared__ __attribute__((aligned(16))) u16 SM[41984];   // 83968 B
  u16* QPa = SM;                 // 64 x 72 (Q then P, head a)
  u16* QPb = SM + 4608;          // 64 x 72 (head b)
  u16* Ksf = SM + 9216;          // Ksa[2] (2x 64x64) then Ksb[2]
  u16* Vs  = SM + 25600;         // V dbuf: 2 x (128 x 64)
  float* OLDS = (float*)(SM + 9216);  // 64 x 128 fp32, overlays K bufs (epilogue only)

  const int p   = blockIdx.x;                 // 0..15
  const int hp  = blockIdx.y;                 // 0..15
  const int kva = hp >> 2, kvb = kva + 4;
  const int t   = threadIdx.x, w = t >> 6, lane = t & 63;
  const int hb  = w >> 2;                     // 0 = head a, 1 = head b
  const int wq  = w & 3;                      // q-row group
  const int mm  = lane & 15, g = lane >> 4, g8 = g * 8;
  const int sr  = t >> 3;                     // staging row 0..63
  const int sc  = t & 7;
  const int so  = sc * 8;
  const int x0  = ((g ^ (mm & 7)) * 8);
  const int x1  = (((g + 4) ^ (mm & 7)) * 8);

  u16* QP = hb ? QPb : QPa;

  float lp1 = lq1[lane] * lk1[lane];
  float lp2 = lq2[lane] * lk2[lane];
#pragma unroll
  for (int off = 1; off < 64; off <<= 1){
    lp1 += __shfl_xor(lp1, off);
    lp2 += __shfl_xor(lp2, off);
  }
  const float lam = __expf(lp1) - __expf(lp2) + LAMBDA_INIT;

  for (int seg = 0; seg < 2; seg++){
    const int qt = seg ? p : (31 - p);
    const int q0 = qt * 64;

    __syncthreads();   // prior segment fully done (incl. OLDS reads) before restage
    // issue K(0) and V(0) into buffer 0; stage Q tiles with plain stores
    {
      int ce = ((sc ^ (sr & 7)) * 8);
      gld16(Kbf + ((size_t)kva * S_LEN + sr) * HD + ce, Ksf + (w*8)*64);
      gld16(Kbf + ((size_t)kvb * S_LEN + sr) * HD + ce, Ksf + 8192 + (w*8)*64);
      gld16(Vt + ((size_t)kva * HD + sr) * S_LEN + ce, Vs + (w*8)*64);
      gld16(Vt + ((size_t)kvb * HD + sr) * S_LEN + ce, Vs + (w*8 + 64)*64);
    }
    *(uint4*)&QPa[sr*72 + so] = *(const uint4*)&Qbf[((size_t)hp        * S_LEN + q0 + sr) * HD + so];
    *(uint4*)&QPb[sr*72 + so] = *(const uint4*)&Qbf[((size_t)(hp + 16) * S_LEN + q0 + sr) * HD + so];
    __syncthreads();   // Q visible, K(0)/V(0) drained (full barrier drains vmcnt)
    v8s qa0 = *(const v8s*)&QP[(wq*16 + mm)*72 + g8];
    v8s qa1 = *(const v8s*)&QP[(wq*16 + mm)*72 + 32 + g8];

    v4f O[8];
#pragma unroll
    for (int n = 0; n < 8; n++) O[n] = (v4f){0.f,0.f,0.f,0.f};
    float l[4] = {0.f,0.f,0.f,0.f};

    for (int k0 = 0; k0 <= q0; k0 += 64){
      const int cur = (k0 >> 6) & 1;
      if (k0){
        // K(k0),V(k0) issued one full iteration ago: drain (≈0 stall), sync.
        asm volatile("s_waitcnt vmcnt(0)" ::: "memory");
        __builtin_amdgcn_s_barrier();
        __builtin_amdgcn_sched_barrier(0);
      }
      // prefetch K(k0+64), V(k0+64) into the other buffers; in flight all iter
      if (k0 + 64 <= q0){
        int ce = ((sc ^ (sr & 7)) * 8);
        gld16(Vt + ((size_t)kva * HD + sr) * S_LEN + k0 + 64 + ce, Vs + (cur^1)*8192 + (w*8)*64);
        gld16(Vt + ((size_t)kvb * HD + sr) * S_LEN + k0 + 64 + ce, Vs + (cur^1)*8192 + (w*8 + 64)*64);
        gld16(Kbf + ((size_t)kva * S_LEN + k0 + 64 + sr) * HD + ce, Ksf + (cur^1)*4096 + (w*8)*64);
        gld16(Kbf + ((size_t)kvb * S_LEN + k0 + 64 + sr) * HD + ce, Ksf + 8192 + (cur^1)*4096 + (w*8)*64);
      }

      const u16* Kh = Ksf + hb*8192 + cur*4096;
      const bool dg = (k0 == q0);
      v4f S[4];
      __builtin_amdgcn_s_setprio(1);
#pragma unroll
      for (int n = 0; n < 4; n++){
        int row = n*16 + mm;
        v8s kb0 = *(const v8s*)&Kh[row*64 + x0];
        v8s kb1 = *(const v8s*)&Kh[row*64 + x1];
        v4f z = (v4f){0.f,0.f,0.f,0.f};
        z = __builtin_amdgcn_mfma_f32_16x16x32_bf16(qa0, kb0, z, 0, 0, 0);
        z = __builtin_amdgcn_mfma_f32_16x16x32_bf16(qa1, kb1, z, 0, 0, 0);
        S[n] = z;
      }
      __builtin_amdgcn_s_setprio(0);
      // P is wave-private (rows wq*16..wq*16+15): no barrier around store/reload
#pragma unroll
      for (int n = 0; n < 4; n++)
#pragma unroll
        for (int r = 0; r < 4; r++){
          float pe = __expf(S[n][r] * 0.125f);
          if (dg && (n*16 + mm > wq*16 + g*4 + r)) pe = 0.f;
          l[r] += pe;
          QP[(wq*16 + g*4 + r)*72 + n*16 + mm] = f2b(pe);
        }
      v8s pa0 = *(const v8s*)&QP[(wq*16 + mm)*72 + g8];
      v8s pa1 = *(const v8s*)&QP[(wq*16 + mm)*72 + 32 + g8];
      const u16* Vh = Vs + cur*8192;
      __builtin_amdgcn_s_setprio(1);
#pragma unroll
      for (int n = 0; n < 8; n++){
        int row = n*16 + mm;
        v8s vb0 = *(const v8s*)&Vh[row*64 + x0];
        v8s vb1 = *(const v8s*)&Vh[row*64 + x1];
        O[n] = __builtin_amdgcn_mfma_f32_16x16x32_bf16(pa0, vb0, O[n], 0, 0, 0);
        O[n] = __builtin_amdgcn_mfma_f32_16x16x32_bf16(pa1, vb1, O[n], 0, 0, 0);
      }
      __builtin_amdgcn_s_setprio(0);
    }

    // ---- epilogue for this segment ----
#pragma unroll
    for (int off = 1; off < 16; off <<= 1)
#pragma unroll
      for (int r = 0; r < 4; r++)
        l[r] += __shfl_xor(l[r], off);
    float il[4];
#pragma unroll
    for (int r = 0; r < 4; r++) il[r] = hb ? (lam / l[r]) : (1.0f / l[r]);

    __syncthreads();   // all QK reads of Ks done; OLDS may overwrite K bufs
    if (hb){
#pragma unroll
      for (int n = 0; n < 8; n++)
#pragma unroll
        for (int r = 0; r < 4; r++)
          OLDS[(wq*16 + g*4 + r)*128 + n*16 + mm] = O[n][r] * il[r];
    }
    __syncthreads();
    if (!hb){
      float av[8][4];
      float ss[4] = {0.f,0.f,0.f,0.f};
#pragma unroll
      for (int n = 0; n < 8; n++)
#pragma unroll
        for (int r = 0; r < 4; r++){
          float a = O[n][r] * il[r] - OLDS[(wq*16 + g*4 + r)*128 + n*16 + mm];
          av[n][r] = a;
          ss[r] += a * a;
        }
#pragma unroll
      for (int off = 1; off < 16; off <<= 1)
#pragma unroll
        for (int r = 0; r < 4; r++)
          ss[r] += __shfl_xor(ss[r], off);
      float rv[4];
#pragma unroll
      for (int r = 0; r < 4; r++)
        rv[r] = rsqrtf(ss[r] * (1.0f/128.0f) + 1e-6f) * ONE_MINUS_LI;
#pragma unroll
      for (int n = 0; n < 8; n++)
#pragma unroll
        for (int r = 0; r < 4; r++){
          int srow = q0 + wq*16 + g*4 + r;
          Ctx[(size_t)srow * HID + hp * DVV + n*16 + mm] = f2b(av[n][r] * rv[r]);
        }
    }
  }
}

extern "C" void kernel_launch(void* const* d_in, const int* in_sizes, int n_in,
                              void* d_out, int out_size, void* d_ws, size_t ws_size,
                              hipStream_t stream)
{
  (void)in_sizes; (void)n_in; (void)out_size; (void)ws_size;
  const float* hs   = (const float*)d_in[0];
  const float* cosb = (const float*)d_in[1];
  const float* sinb = (const float*)d_in[2];
  const float* Wq   = (const float*)d_in[3];
  const float* Wk   = (const float*)d_in[4];
  const float* Wv   = (const float*)d_in[5];
  const float* Wo   = (const float*)d_in[6];
  const float* lq1  = (const float*)d_in[7];
  const float* lk1  = (const float*)d_in[8];
  const float* lq2  = (const float*)d_in[9];
  const float* lk2  = (const float*)d_in[10];

  char* ws = (char*)d_ws;
  u16* hsb   = (u16*)(ws);                   // [0,8) MB bf16 hs
  u16* Wqkvb = (u16*)(ws + (8u  << 20));     // [8,20) bf16 [Wq;Wk;Wv] 3072x2048
  u16* QKVb  = (u16*)(ws + (20u << 20));     // [20,32) bf16 (S,3072)
  u16* Ctx   = (u16*)(ws + (20u << 20));     // [20,28) overlays QKVb after rope/vtrans
  u16* Wob   = (u16*)(ws + (32u << 20));     // [32,40) bf16 Wo
  u16* Kbf   = (u16*)(ws + (44u << 20));     // [44,46) bf16 (8,S,64)
  u16* Vt    = (u16*)(ws + (46u << 20));     // [46,48) bf16 (8,64,S)
  u16* Qbf   = (u16*)(ws + (48u << 20));     // [48,56) bf16 (32,S,64)

  cast5<<<7168, 256, 0, stream>>>(hs, Wq, Wk, Wv, Wo, hsb, Wqkvb, Wob);
  gemm_bf16<1><<<dim3(48, 16), 256, 0, stream>>>(hsb, Wqkvb, QKVb, S_LEN, 3072, HID);
  rope_all<<<10240, 256, 0, stream>>>(QKVb, cosb, sinb, Qbf, Kbf);
  vtrans<<<NKV * (S_LEN/64), 256, 0, stream>>>(QKVb + 2560, 3072, Vt);
  attn_fused<<<dim3(16, 16), 512, 0, stream>>>(Qbf, Kbf, Vt, lq1, lk1, lq2, lk2, Ctx);
  gemm_bf16<0><<<dim3(32, 16), 256, 0, stream>>>(Ctx, Wob, (float*)d_out, S_LEN, 2048, HID);
}

// Round 10
// 225.067 us; speedup vs baseline: 1.2054x; 1.0295x over previous
//
#include <hip/hip_runtime.h>

typedef unsigned short u16;
typedef __attribute__((ext_vector_type(8))) short v8s;
typedef __attribute__((ext_vector_type(4))) float v4f;

#define S_LEN 2048
#define HID   2048
#define NH    32
#define NKV   8
#define HD    64
#define DVV   128
#define LAMBDA_INIT  0.7455692280263525f
#define ONE_MINUS_LI 0.2544307719736475f

__device__ __forceinline__ u16 f2b(float f){
  union { float f; unsigned int i; } v; v.f = f;
  unsigned int x = v.i;
  unsigned int r = (x + 0x7fffu + ((x >> 16) & 1u)) >> 16;
  return (u16)r;
}
__device__ __forceinline__ float b2f(u16 u){
  union { unsigned int i; float f; } v; v.i = ((unsigned int)u) << 16; return v.f;
}

__device__ __forceinline__ void gld16(const u16* g, u16* l){
  __builtin_amdgcn_global_load_lds(
      (const __attribute__((address_space(1))) unsigned int*)g,
      (__attribute__((address_space(3))) unsigned int*)l, 16, 0, 0);
}

// one launch casting hs, Wq, Wk, Wv, Wo to bf16 (regions by blockIdx)
__global__ __launch_bounds__(256) void cast5(
    const float* __restrict__ hs, const float* __restrict__ Wq,
    const float* __restrict__ Wk, const float* __restrict__ Wv,
    const float* __restrict__ Wo,
    u16* __restrict__ hsb, u16* __restrict__ Wqkvb, u16* __restrict__ Wob)
{
  int b = blockIdx.x;
  const float* S; u16* D; int rb;
  if (b < 2048)      { S = hs; D = hsb;             rb = b; }
  else if (b < 4096) { S = Wq; D = Wqkvb;           rb = b - 2048; }
  else if (b < 4608) { S = Wk; D = Wqkvb + 4194304; rb = b - 4096; }
  else if (b < 5120) { S = Wv; D = Wqkvb + 5242880; rb = b - 4608; }
  else               { S = Wo; D = Wob;             rb = b - 5120; }
  size_t i = ((size_t)rb * 256 + threadIdx.x) * 8;
  float4 a = *(const float4*)(S + i);
  float4 c = *(const float4*)(S + i + 4);
  u16 o[8] = {f2b(a.x), f2b(a.y), f2b(a.z), f2b(a.w), f2b(c.x), f2b(c.y), f2b(c.z), f2b(c.w)};
  *(uint4*)(D + i) = *(const uint4*)o;
}

// C[m][n] = sum_k A[m*K+k]*B[n*K+k]; A,B bf16.
// 128x64 tile (BM=128, BN=64), BK=64, double-buffered LDS, one raw
// vmcnt(0)+s_barrier per K-step (R8 pipeline), 2-3 blocks/CU (R9).
// MODE 0: C fp32.  MODE 2: fused QKV epilogue — Q cols (n0<2048) and K cols
// (2048<=n0<2560) get RoPE applied IN REGISTERS and go directly to Qbf/Kbf
// ((h,s,d) layout); V cols (n0>=2560) written bf16 to Cv (QKVb) for vtrans.
// Rotate-half pairing is thread-local: col d=j*16+mm pairs with d+32 =
// (j+2)*16+mm (same mm, same thread) because BN=64 == head dim.
// RoPE on fp32 acc (vs old bf16 round-trip) -> one fewer rounding.
template<int MODE>
__global__ __launch_bounds__(256) void gemm_bf16(const u16* __restrict__ A, const u16* __restrict__ B,
                                                 void* __restrict__ Cv, int M, int N, int K,
                                                 const float* __restrict__ cosb, const float* __restrict__ sinb,
                                                 u16* __restrict__ Qbf, u16* __restrict__ Kbf)
{
  __shared__ __attribute__((aligned(16))) u16 As[2][128*64];
  __shared__ __attribute__((aligned(16))) u16 Bs[2][64*64];
  const int t    = threadIdx.x;
  const int w    = t >> 6, lane = t & 63;
  const int mm   = lane & 15, g = lane >> 4;
  const int m0   = blockIdx.y * 128, n0 = blockIdx.x * 64;
  const int lr   = lane >> 3;      // 0..7
  const int sch  = lane & 7;

  v4f acc[2][4];
#pragma unroll
  for (int i = 0; i < 2; i++)
#pragma unroll
    for (int j = 0; j < 4; j++) acc[i][j] = (v4f){0.f,0.f,0.f,0.f};

#define G_STAGE(kk, buf) do { \
    _Pragma("unroll") \
    for (int i = 0; i < 4; i++){ \
      int r  = w*32 + lr + i*8; \
      int ce = ((sch ^ (r & 7)) * 8); \
      gld16(A + (size_t)(m0 + r) * K + (kk) + ce, &As[buf][w*2048 + i*512]); \
    } \
    _Pragma("unroll") \
    for (int i = 0; i < 2; i++){ \
      int r  = w*16 + lr + i*8; \
      int ce = ((sch ^ (r & 7)) * 8); \
      gld16(B + (size_t)(n0 + r) * K + (kk) + ce, &Bs[buf][w*1024 + i*512]); \
    } \
  } while(0)

  // prologue: stage tile 0 into buffer 0, full drain
  G_STAGE(0, 0);
  __syncthreads();

  for (int k0 = 0; k0 < K; k0 += 64){
    const int cur = (k0 >> 6) & 1;
    if (k0){
      // tile k0 was staged one full iteration ago: drain (~0 stall) + sync
      asm volatile("s_waitcnt vmcnt(0)" ::: "memory");
      __builtin_amdgcn_s_barrier();
      __builtin_amdgcn_sched_barrier(0);
    }
    if (k0 + 64 < K) G_STAGE(k0 + 64, cur ^ 1);

#pragma unroll
    for (int kc = 0; kc < 2; kc++){
      v8s af[2], bf[4];
#pragma unroll
      for (int i = 0; i < 2; i++){
        int r = w*32 + i*16 + mm;
        af[i] = *(const v8s*)&As[cur][r*64 + (((kc*4 + g) ^ (r & 7)) * 8)];
      }
#pragma unroll
      for (int j = 0; j < 4; j++){
        int r = j*16 + mm;
        bf[j] = *(const v8s*)&Bs[cur][r*64 + (((kc*4 + g) ^ (r & 7)) * 8)];
      }
#pragma unroll
      for (int i = 0; i < 2; i++)
#pragma unroll
        for (int j = 0; j < 4; j++)
          acc[i][j] = __builtin_amdgcn_mfma_f32_16x16x32_bf16(af[i], bf[j], acc[i][j], 0, 0, 0);
    }
  }
#undef G_STAGE

  if (MODE == 2 && n0 < 2560){
    // Q or K columns: RoPE in registers, write (h,s,d) layout
    u16* base = (n0 < 2048) ? (Qbf + (size_t)(n0 >> 6) * S_LEN * HD)
                            : (Kbf + (size_t)((n0 - 2048) >> 6) * S_LEN * HD);
#pragma unroll
    for (int i = 0; i < 2; i++)
#pragma unroll
      for (int j = 0; j < 2; j++)
#pragma unroll
        for (int r = 0; r < 4; r++){
          int s = m0 + w*32 + i*16 + g*4 + r;
          int d = j*16 + mm;
          float x1 = acc[i][j][r], x2 = acc[i][j+2][r];
          float c1 = cosb[s*HD + d],      s1 = sinb[s*HD + d];
          float c2 = cosb[s*HD + d + 32], s2 = sinb[s*HD + d + 32];
          base[(size_t)s*HD + d]      = f2b(x1*c1 - x2*s1);
          base[(size_t)s*HD + d + 32] = f2b(x2*c2 + x1*s2);
        }
  } else if (MODE != 0){
    // V columns (MODE 2): bf16 to Cv (QKVb layout, stride N)
    u16* C = (u16*)Cv;
#pragma unroll
    for (int i = 0; i < 2; i++)
#pragma unroll
      for (int j = 0; j < 4; j++)
#pragma unroll
        for (int r = 0; r < 4; r++)
          C[(size_t)(m0 + w*32 + i*16 + g*4 + r) * N + n0 + j*16 + mm] = f2b(acc[i][j][r]);
  } else {
    float* C = (float*)Cv;
#pragma unroll
    for (int i = 0; i < 2; i++)
#pragma unroll
      for (int j = 0; j < 4; j++)
#pragma unroll
        for (int r = 0; r < 4; r++)
          C[(size_t)(m0 + w*32 + i*16 + g*4 + r) * N + n0 + j*16 + mm] = acc[i][j][r];
  }
}

// V bf16 rows (stride u16 elems, head h at col h*64) -> Vt bf16 (8, 64, S)
__global__ __launch_bounds__(256) void vtrans(const u16* __restrict__ Vb, int stride, u16* __restrict__ Vt)
{
  __shared__ u16 T[64][72];
  const int b = blockIdx.x;
  const int h = b >> 5;
  const int s0 = (b & 31) * 64;
  const int t = threadIdx.x;
#pragma unroll
  for (int i = 0; i < 4; i++){
    int u = t + i * 256;
    int r = u >> 4, c4 = (u & 15) * 4;
    uint2 v = *(const uint2*)&Vb[(size_t)(s0 + r) * stride + h * HD + c4];
    T[c4+0][r] = (u16)(v.x & 0xffff); T[c4+1][r] = (u16)(v.x >> 16);
    T[c4+2][r] = (u16)(v.y & 0xffff); T[c4+3][r] = (u16)(v.y >> 16);
  }
  __syncthreads();
#pragma unroll
  for (int i = 0; i < 2; i++){
    int u = t + i * 256;
    int d = u >> 3, ch = (u & 7) * 8;
    *(uint4*)&Vt[((size_t)h * HD + d) * S_LEN + s0 + ch] = *(const uint4*)&T[d][ch];
  }
}

// Fused differential flash attention, 8 waves/block — Round-8 structure
// (grid (16,16), seg loop 31-p then p, V double-buffered + staged one full
// iteration ahead, no mid-iteration barrier, raw vmcnt(0)+s_barrier per iter,
// setprio around MFMA clusters).
__global__ __launch_bounds__(512) void attn_fused(
    const u16* __restrict__ Qbf, const u16* __restrict__ Kbf, const u16* __restrict__ Vt,
    const float* __restrict__ lq1, const float* __restrict__ lk1,
    const float* __restrict__ lq2, const float* __restrict__ lk2,
    u16* __restrict__ Ctx)
{
  __shared__ __attribute__((aligned(16))) u16 SM[41984];   // 83968 B
  u16* QPa = SM;                 // 64 x 72 (Q then P, head a)
  u16* QPb = SM + 4608;          // 64 x 72 (head b)
  u16* Ksf = SM + 9216;          // Ksa[2] (2x 64x64) then Ksb[2]
  u16* Vs  = SM + 25600;         // V dbuf: 2 x (128 x 64)
  float* OLDS = (float*)(SM + 9216);  // 64 x 128 fp32, overlays K bufs (epilogue only)

  const int p   = blockIdx.x;                 // 0..15
  const int hp  = blockIdx.y;                 // 0..15
  const int kva = hp >> 2, kvb = kva + 4;
  const int t   = threadIdx.x, w = t >> 6, lane = t & 63;
  const int hb  = w >> 2;                     // 0 = head a, 1 = head b
  const int wq  = w & 3;                      // q-row group
  const int mm  = lane & 15, g = lane >> 4, g8 = g * 8;
  const int sr  = t >> 3;                     // staging row 0..63
  const int sc  = t & 7;
  const int so  = sc * 8;
  const int x0  = ((g ^ (mm & 7)) * 8);
  const int x1  = (((g + 4) ^ (mm & 7)) * 8);

  u16* QP = hb ? QPb : QPa;

  float lp1 = lq1[lane] * lk1[lane];
  float lp2 = lq2[lane] * lk2[lane];
#pragma unroll
  for (int off = 1; off < 64; off <<= 1){
    lp1 += __shfl_xor(lp1, off);
    lp2 += __shfl_xor(lp2, off);
  }
  const float lam = __expf(lp1) - __expf(lp2) + LAMBDA_INIT;

  for (int seg = 0; seg < 2; seg++){
    const int qt = seg ? p : (31 - p);
    const int q0 = qt * 64;

    __syncthreads();   // prior segment fully done (incl. OLDS reads) before restage
    // issue K(0) and V(0) into buffer 0; stage Q tiles with plain stores
    {
      int ce = ((sc ^ (sr & 7)) * 8);
      gld16(Kbf + ((size_t)kva * S_LEN + sr) * HD + ce, Ksf + (w*8)*64);
      gld16(Kbf + ((size_t)kvb * S_LEN + sr) * HD + ce, Ksf + 8192 + (w*8)*64);
      gld16(Vt + ((size_t)kva * HD + sr) * S_LEN + ce, Vs + (w*8)*64);
      gld16(Vt + ((size_t)kvb * HD + sr) * S_LEN + ce, Vs + (w*8 + 64)*64);
    }
    *(uint4*)&QPa[sr*72 + so] = *(const uint4*)&Qbf[((size_t)hp        * S_LEN + q0 + sr) * HD + so];
    *(uint4*)&QPb[sr*72 + so] = *(const uint4*)&Qbf[((size_t)(hp + 16) * S_LEN + q0 + sr) * HD + so];
    __syncthreads();   // Q visible, K(0)/V(0) drained (full barrier drains vmcnt)
    v8s qa0 = *(const v8s*)&QP[(wq*16 + mm)*72 + g8];
    v8s qa1 = *(const v8s*)&QP[(wq*16 + mm)*72 + 32 + g8];

    v4f O[8];
#pragma unroll
    for (int n = 0; n < 8; n++) O[n] = (v4f){0.f,0.f,0.f,0.f};
    float l[4] = {0.f,0.f,0.f,0.f};

    for (int k0 = 0; k0 <= q0; k0 += 64){
      const int cur = (k0 >> 6) & 1;
      if (k0){
        // K(k0),V(k0) issued one full iteration ago: drain (≈0 stall), sync.
        asm volatile("s_waitcnt vmcnt(0)" ::: "memory");
        __builtin_amdgcn_s_barrier();
        __builtin_amdgcn_sched_barrier(0);
      }
      // prefetch K(k0+64), V(k0+64) into the other buffers; in flight all iter
      if (k0 + 64 <= q0){
        int ce = ((sc ^ (sr & 7)) * 8);
        gld16(Vt + ((size_t)kva * HD + sr) * S_LEN + k0 + 64 + ce, Vs + (cur^1)*8192 + (w*8)*64);
        gld16(Vt + ((size_t)kvb * HD + sr) * S_LEN + k0 + 64 + ce, Vs + (cur^1)*8192 + (w*8 + 64)*64);
        gld16(Kbf + ((size_t)kva * S_LEN + k0 + 64 + sr) * HD + ce, Ksf + (cur^1)*4096 + (w*8)*64);
        gld16(Kbf + ((size_t)kvb * S_LEN + k0 + 64 + sr) * HD + ce, Ksf + 8192 + (cur^1)*4096 + (w*8)*64);
      }

      const u16* Kh = Ksf + hb*8192 + cur*4096;
      const bool dg = (k0 == q0);
      v4f S[4];
      __builtin_amdgcn_s_setprio(1);
#pragma unroll
      for (int n = 0; n < 4; n++){
        int row = n*16 + mm;
        v8s kb0 = *(const v8s*)&Kh[row*64 + x0];
        v8s kb1 = *(const v8s*)&Kh[row*64 + x1];
        v4f z = (v4f){0.f,0.f,0.f,0.f};
        z = __builtin_amdgcn_mfma_f32_16x16x32_bf16(qa0, kb0, z, 0, 0, 0);
        z = __builtin_amdgcn_mfma_f32_16x16x32_bf16(qa1, kb1, z, 0, 0, 0);
        S[n] = z;
      }
      __builtin_amdgcn_s_setprio(0);
      // P is wave-private (rows wq*16..wq*16+15): no barrier around store/reload
#pragma unroll
      for (int n = 0; n < 4; n++)
#pragma unroll
        for (int r = 0; r < 4; r++){
          float pe = __expf(S[n][r] * 0.125f);
          if (dg && (n*16 + mm > wq*16 + g*4 + r)) pe = 0.f;
          l[r] += pe;
          QP[(wq*16 + g*4 + r)*72 + n*16 + mm] = f2b(pe);
        }
      v8s pa0 = *(const v8s*)&QP[(wq*16 + mm)*72 + g8];
      v8s pa1 = *(const v8s*)&QP[(wq*16 + mm)*72 + 32 + g8];
      const u16* Vh = Vs + cur*8192;
      __builtin_amdgcn_s_setprio(1);
#pragma unroll
      for (int n = 0; n < 8; n++){
        int row = n*16 + mm;
        v8s vb0 = *(const v8s*)&Vh[row*64 + x0];
        v8s vb1 = *(const v8s*)&Vh[row*64 + x1];
        O[n] = __builtin_amdgcn_mfma_f32_16x16x32_bf16(pa0, vb0, O[n], 0, 0, 0);
        O[n] = __builtin_amdgcn_mfma_f32_16x16x32_bf16(pa1, vb1, O[n], 0, 0, 0);
      }
      __builtin_amdgcn_s_setprio(0);
    }

    // ---- epilogue for this segment ----
#pragma unroll
    for (int off = 1; off < 16; off <<= 1)
#pragma unroll
      for (int r = 0; r < 4; r++)
        l[r] += __shfl_xor(l[r], off);
    float il[4];
#pragma unroll
    for (int r = 0; r < 4; r++) il[r] = hb ? (lam / l[r]) : (1.0f / l[r]);

    __syncthreads();   // all QK reads of Ks done; OLDS may overwrite K bufs
    if (hb){
#pragma unroll
      for (int n = 0; n < 8; n++)
#pragma unroll
        for (int r = 0; r < 4; r++)
          OLDS[(wq*16 + g*4 + r)*128 + n*16 + mm] = O[n][r] * il[r];
    }
    __syncthreads();
    if (!hb){
      float av[8][4];
      float ss[4] = {0.f,0.f,0.f,0.f};
#pragma unroll
      for (int n = 0; n < 8; n++)
#pragma unroll
        for (int r = 0; r < 4; r++){
          float a = O[n][r] * il[r] - OLDS[(wq*16 + g*4 + r)*128 + n*16 + mm];
          av[n][r] = a;
          ss[r] += a * a;
        }
#pragma unroll
      for (int off = 1; off < 16; off <<= 1)
#pragma unroll
        for (int r = 0; r < 4; r++)
          ss[r] += __shfl_xor(ss[r], off);
      float rv[4];
#pragma unroll
      for (int r = 0; r < 4; r++)
        rv[r] = rsqrtf(ss[r] * (1.0f/128.0f) + 1e-6f) * ONE_MINUS_LI;
#pragma unroll
      for (int n = 0; n < 8; n++)
#pragma unroll
        for (int r = 0; r < 4; r++){
          int srow = q0 + wq*16 + g*4 + r;
          Ctx[(size_t)srow * HID + hp * DVV + n*16 + mm] = f2b(av[n][r] * rv[r]);
        }
    }
  }
}

extern "C" void kernel_launch(void* const* d_in, const int* in_sizes, int n_in,
                              void* d_out, int out_size, void* d_ws, size_t ws_size,
                              hipStream_t stream)
{
  (void)in_sizes; (void)n_in; (void)out_size; (void)ws_size;
  const float* hs   = (const float*)d_in[0];
  const float* cosb = (const float*)d_in[1];
  const float* sinb = (const float*)d_in[2];
  const float* Wq   = (const float*)d_in[3];
  const float* Wk   = (const float*)d_in[4];
  const float* Wv   = (const float*)d_in[5];
  const float* Wo   = (const float*)d_in[6];
  const float* lq1  = (const float*)d_in[7];
  const float* lk1  = (const float*)d_in[8];
  const float* lq2  = (const float*)d_in[9];
  const float* lk2  = (const float*)d_in[10];

  char* ws = (char*)d_ws;
  u16* hsb   = (u16*)(ws);                   // [0,8) MB bf16 hs
  u16* Wqkvb = (u16*)(ws + (8u  << 20));     // [8,20) bf16 [Wq;Wk;Wv] 3072x2048
  u16* QKVb  = (u16*)(ws + (20u << 20));     // [20,32) bf16 (S,3072) — only V cols used now
  u16* Ctx   = (u16*)(ws + (20u << 20));     // [20,28) overlays QKVb after vtrans
  u16* Wob   = (u16*)(ws + (32u << 20));     // [32,40) bf16 Wo
  u16* Kbf   = (u16*)(ws + (44u << 20));     // [44,46) bf16 (8,S,64)
  u16* Vt    = (u16*)(ws + (46u << 20));     // [46,48) bf16 (8,64,S)
  u16* Qbf   = (u16*)(ws + (48u << 20));     // [48,56) bf16 (32,S,64)

  cast5<<<7168, 256, 0, stream>>>(hs, Wq, Wk, Wv, Wo, hsb, Wqkvb, Wob);
  gemm_bf16<2><<<dim3(48, 16), 256, 0, stream>>>(hsb, Wqkvb, QKVb, S_LEN, 3072, HID,
                                                 cosb, sinb, Qbf, Kbf);
  vtrans<<<NKV * (S_LEN/64), 256, 0, stream>>>(QKVb + 2560, 3072, Vt);
  attn_fused<<<dim3(16, 16), 512, 0, stream>>>(Qbf, Kbf, Vt, lq1, lk1, lq2, lk2, Ctx);
  gemm_bf16<0><<<dim3(32, 16), 256, 0, stream>>>(Ctx, Wob, (float*)d_out, S_LEN, 2048, HID,
                                                 nullptr, nullptr, nullptr, nullptr);
}

// Round 11
// 220.995 us; speedup vs baseline: 1.2276x; 1.0184x over previous
//
#include <hip/hip_runtime.h>

typedef unsigned short u16;
typedef __attribute__((ext_vector_type(8))) short v8s;
typedef __attribute__((ext_vector_type(4))) float v4f;

#define S_LEN 2048
#define HID   2048
#define NH    32
#define NKV   8
#define HD    64
#define DVV   128
#define LAMBDA_INIT  0.7455692280263525f
#define ONE_MINUS_LI 0.2544307719736475f

__device__ __forceinline__ u16 f2b(float f){
  union { float f; unsigned int i; } v; v.f = f;
  unsigned int x = v.i;
  unsigned int r = (x + 0x7fffu + ((x >> 16) & 1u)) >> 16;
  return (u16)r;
}
__device__ __forceinline__ float b2f(u16 u){
  union { unsigned int i; float f; } v; v.i = ((unsigned int)u) << 16; return v.f;
}

__device__ __forceinline__ void gld16(const u16* g, u16* l){
  __builtin_amdgcn_global_load_lds(
      (const __attribute__((address_space(1))) unsigned int*)g,
      (__attribute__((address_space(3))) unsigned int*)l, 16, 0, 0);
}

// one launch casting hs, Wq, Wk, Wv, Wo to bf16 (regions by blockIdx)
__global__ __launch_bounds__(256) void cast5(
    const float* __restrict__ hs, const float* __restrict__ Wq,
    const float* __restrict__ Wk, const float* __restrict__ Wv,
    const float* __restrict__ Wo,
    u16* __restrict__ hsb, u16* __restrict__ Wqkvb, u16* __restrict__ Wob)
{
  int b = blockIdx.x;
  const float* S; u16* D; int rb;
  if (b < 2048)      { S = hs; D = hsb;             rb = b; }
  else if (b < 4096) { S = Wq; D = Wqkvb;           rb = b - 2048; }
  else if (b < 4608) { S = Wk; D = Wqkvb + 4194304; rb = b - 4096; }
  else if (b < 5120) { S = Wv; D = Wqkvb + 5242880; rb = b - 4608; }
  else               { S = Wo; D = Wob;             rb = b - 5120; }
  size_t i = ((size_t)rb * 256 + threadIdx.x) * 8;
  float4 a = *(const float4*)(S + i);
  float4 c = *(const float4*)(S + i + 4);
  u16 o[8] = {f2b(a.x), f2b(a.y), f2b(a.z), f2b(a.w), f2b(c.x), f2b(c.y), f2b(c.z), f2b(c.w)};
  *(uint4*)(D + i) = *(const uint4*)o;
}

// C[m][n] = sum_k A[m*K+k]*B[n*K+k]; A,B bf16.
// 128x64 tile, BK=64, double-buffered LDS, one raw vmcnt(0)+s_barrier per
// K-step (R8 pipeline), 2-3 blocks/CU (R9).
// MODE 0: C fp32 to Cv.
// MODE 2: fused QKV epilogue — Q cols (n0<2048) and K cols (2048..2559) get
// RoPE in registers -> Qbf/Kbf (h,s,d); V cols (n0>=2560) are TRANSPOSED
// through LDS (reusing As) and written directly to Vt (8,64,S) — vtrans
// dispatch eliminated, values identical (same single f2b rounding).
template<int MODE>
__global__ __launch_bounds__(256) void gemm_bf16(const u16* __restrict__ A, const u16* __restrict__ B,
                                                 void* __restrict__ Cv, int M, int N, int K,
                                                 const float* __restrict__ cosb, const float* __restrict__ sinb,
                                                 u16* __restrict__ Qbf, u16* __restrict__ Kbf,
                                                 u16* __restrict__ Vtp)
{
  __shared__ __attribute__((aligned(16))) u16 As[2][128*64];
  __shared__ __attribute__((aligned(16))) u16 Bs[2][64*64];
  const int t    = threadIdx.x;
  const int w    = t >> 6, lane = t & 63;
  const int mm   = lane & 15, g = lane >> 4;
  const int m0   = blockIdx.y * 128, n0 = blockIdx.x * 64;
  const int lr   = lane >> 3;      // 0..7
  const int sch  = lane & 7;

  v4f acc[2][4];
#pragma unroll
  for (int i = 0; i < 2; i++)
#pragma unroll
    for (int j = 0; j < 4; j++) acc[i][j] = (v4f){0.f,0.f,0.f,0.f};

#define G_STAGE(kk, buf) do { \
    _Pragma("unroll") \
    for (int i = 0; i < 4; i++){ \
      int r  = w*32 + lr + i*8; \
      int ce = ((sch ^ (r & 7)) * 8); \
      gld16(A + (size_t)(m0 + r) * K + (kk) + ce, &As[buf][w*2048 + i*512]); \
    } \
    _Pragma("unroll") \
    for (int i = 0; i < 2; i++){ \
      int r  = w*16 + lr + i*8; \
      int ce = ((sch ^ (r & 7)) * 8); \
      gld16(B + (size_t)(n0 + r) * K + (kk) + ce, &Bs[buf][w*1024 + i*512]); \
    } \
  } while(0)

  // prologue: stage tile 0 into buffer 0, full drain
  G_STAGE(0, 0);
  __syncthreads();

  for (int k0 = 0; k0 < K; k0 += 64){
    const int cur = (k0 >> 6) & 1;
    if (k0){
      // tile k0 was staged one full iteration ago: drain (~0 stall) + sync
      asm volatile("s_waitcnt vmcnt(0)" ::: "memory");
      __builtin_amdgcn_s_barrier();
      __builtin_amdgcn_sched_barrier(0);
    }
    if (k0 + 64 < K) G_STAGE(k0 + 64, cur ^ 1);

#pragma unroll
    for (int kc = 0; kc < 2; kc++){
      v8s af[2], bf[4];
#pragma unroll
      for (int i = 0; i < 2; i++){
        int r = w*32 + i*16 + mm;
        af[i] = *(const v8s*)&As[cur][r*64 + (((kc*4 + g) ^ (r & 7)) * 8)];
      }
#pragma unroll
      for (int j = 0; j < 4; j++){
        int r = j*16 + mm;
        bf[j] = *(const v8s*)&Bs[cur][r*64 + (((kc*4 + g) ^ (r & 7)) * 8)];
      }
#pragma unroll
      for (int i = 0; i < 2; i++)
#pragma unroll
        for (int j = 0; j < 4; j++)
          acc[i][j] = __builtin_amdgcn_mfma_f32_16x16x32_bf16(af[i], bf[j], acc[i][j], 0, 0, 0);
    }
  }
#undef G_STAGE

  if (MODE == 2 && n0 < 2560){
    // Q or K columns: RoPE in registers, write (h,s,d) layout
    u16* base = (n0 < 2048) ? (Qbf + (size_t)(n0 >> 6) * S_LEN * HD)
                            : (Kbf + (size_t)((n0 - 2048) >> 6) * S_LEN * HD);
#pragma unroll
    for (int i = 0; i < 2; i++)
#pragma unroll
      for (int j = 0; j < 2; j++)
#pragma unroll
        for (int r = 0; r < 4; r++){
          int s = m0 + w*32 + i*16 + g*4 + r;
          int d = j*16 + mm;
          float x1 = acc[i][j][r], x2 = acc[i][j+2][r];
          float c1 = cosb[s*HD + d],      s1 = sinb[s*HD + d];
          float c2 = cosb[s*HD + d + 32], s2 = sinb[s*HD + d + 32];
          base[(size_t)s*HD + d]      = f2b(x1*c1 - x2*s1);
          base[(size_t)s*HD + d + 32] = f2b(x2*c2 + x1*s2);
        }
  } else if (MODE == 2){
    // V columns: transpose through LDS (As is dead) -> Vt (8,64,S)
    __syncthreads();            // all As/Bs reads done
    u16* T = (u16*)As;          // 64 x 136 (d-major, +8 pad)
    const int h = (n0 - 2560) >> 6;
#pragma unroll
    for (int i = 0; i < 2; i++)
#pragma unroll
      for (int j = 0; j < 4; j++)
#pragma unroll
        for (int r = 0; r < 4; r++){
          int s = w*32 + i*16 + g*4 + r;      // 0..127 block-local
          int d = j*16 + mm;
          T[d*136 + s] = f2b(acc[i][j][r]);
        }
    __syncthreads();
#pragma unroll
    for (int it = 0; it < 4; it++){
      int u  = t + it*256;
      int d  = u >> 4, ch = (u & 15) * 8;
      *(uint4*)&Vtp[((size_t)h*HD + d)*S_LEN + m0 + ch] = *(const uint4*)&T[d*136 + ch];
    }
  } else {
    float* C = (float*)Cv;
#pragma unroll
    for (int i = 0; i < 2; i++)
#pragma unroll
      for (int j = 0; j < 4; j++)
#pragma unroll
        for (int r = 0; r < 4; r++)
          C[(size_t)(m0 + w*32 + i*16 + g*4 + r) * N + n0 + j*16 + mm] = acc[i][j][r];
  }
}

// Fused differential flash attention, 8 waves/block.
// R11: 4-deep K/V LDS buffers, prefetch distance 2, COUNTED vmcnt waits (T4):
// at top of iter k wait vmcnt(4) (= only tile k's 4 loads; tile k+1 stays in
// flight), vmcnt(0) only on the final iter. Each tile now has ~2 iterations
// of slack instead of 1. Same 1-tile-per-barrier cadence as R8 (R7's
// regression bunched loads AND computed pairs per drain — this does neither).
// Everything else = R8: no mid-iteration barrier (P wave-private), setprio
// around MFMA clusters, seg loop 31-p then p.
__global__ __launch_bounds__(512) void attn_fused(
    const u16* __restrict__ Qbf, const u16* __restrict__ Kbf, const u16* __restrict__ Vt,
    const float* __restrict__ lq1, const float* __restrict__ lk1,
    const float* __restrict__ lq2, const float* __restrict__ lk2,
    u16* __restrict__ Ctx)
{
  __shared__ __attribute__((aligned(16))) u16 SM[74752];   // 149504 B
  u16* QPa = SM;                  // 64 x 72 (Q then P, head a)
  u16* QPb = SM + 4608;           // 64 x 72 (head b)
  u16* Ksf = SM + 9216;           // [head:2][buf:4][64][64] u16 (64 KiB)
  u16* Vs  = SM + 41984;          // [buf:4][128][64] u16 (64 KiB)
  float* OLDS = (float*)(SM + 9216);  // 64 x 128 fp32 (32 KiB), overlays Ksf

  const int p   = blockIdx.x;                 // 0..15
  const int hp  = blockIdx.y;                 // 0..15
  const int kva = hp >> 2, kvb = kva + 4;
  const int t   = threadIdx.x, w = t >> 6, lane = t & 63;
  const int hb  = w >> 2;                     // 0 = head a, 1 = head b
  const int wq  = w & 3;                      // q-row group
  const int mm  = lane & 15, g = lane >> 4, g8 = g * 8;
  const int sr  = t >> 3;                     // staging row 0..63
  const int sc  = t & 7;
  const int so  = sc * 8;
  const int x0  = ((g ^ (mm & 7)) * 8);
  const int x1  = (((g + 4) ^ (mm & 7)) * 8);
  const int ce  = ((sc ^ (sr & 7)) * 8);      // XOR chunk swizzle for staging

  u16* QP = hb ? QPb : QPa;

  float lp1 = lq1[lane] * lk1[lane];
  float lp2 = lq2[lane] * lk2[lane];
#pragma unroll
  for (int off = 1; off < 64; off <<= 1){
    lp1 += __shfl_xor(lp1, off);
    lp2 += __shfl_xor(lp2, off);
  }
  const float lam = __expf(lp1) - __expf(lp2) + LAMBDA_INIT;

// stage K/V tile kk into LDS buffer (kk/64)&3 (4 gld16 per thread)
#define TILE_ISSUE(kk) do { \
    const int tb_ = ((kk) >> 6) & 3; \
    gld16(Kbf + ((size_t)kva * S_LEN + (kk) + sr) * HD + ce, Ksf + tb_*4096 + (w*8)*64); \
    gld16(Kbf + ((size_t)kvb * S_LEN + (kk) + sr) * HD + ce, Ksf + 16384 + tb_*4096 + (w*8)*64); \
    gld16(Vt  + ((size_t)kva * HD + sr) * S_LEN + (kk) + ce, Vs + tb_*8192 + (w*8)*64); \
    gld16(Vt  + ((size_t)kvb * HD + sr) * S_LEN + (kk) + ce, Vs + tb_*8192 + (w*8 + 64)*64); \
  } while(0)

  for (int seg = 0; seg < 2; seg++){
    const int qt = seg ? p : (31 - p);
    const int q0 = qt * 64;

    __syncthreads();   // prior segment fully done (incl. OLDS reads) before restage
    // issue tiles 0 and 1; stage Q with plain stores
    TILE_ISSUE(0);
    if (64 <= q0) TILE_ISSUE(64);
    *(uint4*)&QPa[sr*72 + so] = *(const uint4*)&Qbf[((size_t)hp        * S_LEN + q0 + sr) * HD + so];
    *(uint4*)&QPb[sr*72 + so] = *(const uint4*)&Qbf[((size_t)(hp + 16) * S_LEN + q0 + sr) * HD + so];
    __syncthreads();   // Q visible, tiles 0,1 drained (full barrier drains vmcnt)
    v8s qa0 = *(const v8s*)&QP[(wq*16 + mm)*72 + g8];
    v8s qa1 = *(const v8s*)&QP[(wq*16 + mm)*72 + 32 + g8];

    v4f O[8];
#pragma unroll
    for (int n = 0; n < 8; n++) O[n] = (v4f){0.f,0.f,0.f,0.f};
    float l[4] = {0.f,0.f,0.f,0.f};

    for (int k0 = 0; k0 <= q0; k0 += 64){
      const int cur = (k0 >> 6) & 3;
      if (k0){
        // tile k0 was issued 2 iterations ago. Wait ONLY its 4 loads:
        // outstanding = tile k0 (4) + tile k0+64 (4, if issued) -> vmcnt(4)
        // keeps the newer tile in flight. Final iter: nothing newer, drain 0.
        if (k0 + 64 <= q0) asm volatile("s_waitcnt vmcnt(4)" ::: "memory");
        else               asm volatile("s_waitcnt vmcnt(0)" ::: "memory");
        __builtin_amdgcn_s_barrier();
        __builtin_amdgcn_sched_barrier(0);
      }
      // issue tile k0+128 (prefetch distance 2); buffer (k0/64+2)&3 was last
      // read in iter k0-128, two barriers ago -> WAR safe.
      if (k0 + 128 <= q0) TILE_ISSUE(k0 + 128);

      const u16* Kh = Ksf + hb*16384 + cur*4096;
      const bool dg = (k0 == q0);
      v4f S[4];
      __builtin_amdgcn_s_setprio(1);
#pragma unroll
      for (int n = 0; n < 4; n++){
        int row = n*16 + mm;
        v8s kb0 = *(const v8s*)&Kh[row*64 + x0];
        v8s kb1 = *(const v8s*)&Kh[row*64 + x1];
        v4f z = (v4f){0.f,0.f,0.f,0.f};
        z = __builtin_amdgcn_mfma_f32_16x16x32_bf16(qa0, kb0, z, 0, 0, 0);
        z = __builtin_amdgcn_mfma_f32_16x16x32_bf16(qa1, kb1, z, 0, 0, 0);
        S[n] = z;
      }
      __builtin_amdgcn_s_setprio(0);
      // P is wave-private (rows wq*16..wq*16+15): no barrier around store/reload
#pragma unroll
      for (int n = 0; n < 4; n++)
#pragma unroll
        for (int r = 0; r < 4; r++){
          float pe = __expf(S[n][r] * 0.125f);
          if (dg && (n*16 + mm > wq*16 + g*4 + r)) pe = 0.f;
          l[r] += pe;
          QP[(wq*16 + g*4 + r)*72 + n*16 + mm] = f2b(pe);
        }
      v8s pa0 = *(const v8s*)&QP[(wq*16 + mm)*72 + g8];
      v8s pa1 = *(const v8s*)&QP[(wq*16 + mm)*72 + 32 + g8];
      const u16* Vh = Vs + cur*8192;
      __builtin_amdgcn_s_setprio(1);
#pragma unroll
      for (int n = 0; n < 8; n++){
        int row = n*16 + mm;
        v8s vb0 = *(const v8s*)&Vh[row*64 + x0];
        v8s vb1 = *(const v8s*)&Vh[row*64 + x1];
        O[n] = __builtin_amdgcn_mfma_f32_16x16x32_bf16(pa0, vb0, O[n], 0, 0, 0);
        O[n] = __builtin_amdgcn_mfma_f32_16x16x32_bf16(pa1, vb1, O[n], 0, 0, 0);
      }
      __builtin_amdgcn_s_setprio(0);
    }
#undef TILE_ISSUE

    // ---- epilogue for this segment ----
#pragma unroll
    for (int off = 1; off < 16; off <<= 1)
#pragma unroll
      for (int r = 0; r < 4; r++)
        l[r] += __shfl_xor(l[r], off);
    float il[4];
#pragma unroll
    for (int r = 0; r < 4; r++) il[r] = hb ? (lam / l[r]) : (1.0f / l[r]);

    __syncthreads();   // all QK reads of Ks done; OLDS may overwrite K bufs
    if (hb){
#pragma unroll
      for (int n = 0; n < 8; n++)
#pragma unroll
        for (int r = 0; r < 4; r++)
          OLDS[(wq*16 + g*4 + r)*128 + n*16 + mm] = O[n][r] * il[r];
    }
    __syncthreads();
    if (!hb){
      float av[8][4];
      float ss[4] = {0.f,0.f,0.f,0.f};
#pragma unroll
      for (int n = 0; n < 8; n++)
#pragma unroll
        for (int r = 0; r < 4; r++){
          float a = O[n][r] * il[r] - OLDS[(wq*16 + g*4 + r)*128 + n*16 + mm];
          av[n][r] = a;
          ss[r] += a * a;
        }
#pragma unroll
      for (int off = 1; off < 16; off <<= 1)
#pragma unroll
        for (int r = 0; r < 4; r++)
          ss[r] += __shfl_xor(ss[r], off);
      float rv[4];
#pragma unroll
      for (int r = 0; r < 4; r++)
        rv[r] = rsqrtf(ss[r] * (1.0f/128.0f) + 1e-6f) * ONE_MINUS_LI;
#pragma unroll
      for (int n = 0; n < 8; n++)
#pragma unroll
        for (int r = 0; r < 4; r++){
          int srow = q0 + wq*16 + g*4 + r;
          Ctx[(size_t)srow * HID + hp * DVV + n*16 + mm] = f2b(av[n][r] * rv[r]);
        }
    }
  }
}

extern "C" void kernel_launch(void* const* d_in, const int* in_sizes, int n_in,
                              void* d_out, int out_size, void* d_ws, size_t ws_size,
                              hipStream_t stream)
{
  (void)in_sizes; (void)n_in; (void)out_size; (void)ws_size;
  const float* hs   = (const float*)d_in[0];
  const float* cosb = (const float*)d_in[1];
  const float* sinb = (const float*)d_in[2];
  const float* Wq   = (const float*)d_in[3];
  const float* Wk   = (const float*)d_in[4];
  const float* Wv   = (const float*)d_in[5];
  const float* Wo   = (const float*)d_in[6];
  const float* lq1  = (const float*)d_in[7];
  const float* lk1  = (const float*)d_in[8];
  const float* lq2  = (const float*)d_in[9];
  const float* lk2  = (const float*)d_in[10];

  char* ws = (char*)d_ws;
  u16* hsb   = (u16*)(ws);                   // [0,8) MB bf16 hs
  u16* Wqkvb = (u16*)(ws + (8u  << 20));     // [8,20) bf16 [Wq;Wk;Wv] 3072x2048
  u16* Ctx   = (u16*)(ws + (20u << 20));     // [20,28) bf16 Ctx (S,2048)
  u16* Wob   = (u16*)(ws + (32u << 20));     // [32,40) bf16 Wo
  u16* Kbf   = (u16*)(ws + (44u << 20));     // [44,46) bf16 (8,S,64)
  u16* Vt    = (u16*)(ws + (46u << 20));     // [46,48) bf16 (8,64,S)
  u16* Qbf   = (u16*)(ws + (48u << 20));     // [48,56) bf16 (32,S,64)

  cast5<<<7168, 256, 0, stream>>>(hs, Wq, Wk, Wv, Wo, hsb, Wqkvb, Wob);
  gemm_bf16<2><<<dim3(48, 16), 256, 0, stream>>>(hsb, Wqkvb, nullptr, S_LEN, 3072, HID,
                                                 cosb, sinb, Qbf, Kbf, Vt);
  attn_fused<<<dim3(16, 16), 512, 0, stream>>>(Qbf, Kbf, Vt, lq1, lk1, lq2, lk2, Ctx);
  gemm_bf16<0><<<dim3(32, 16), 256, 0, stream>>>(Ctx, Wob, (float*)d_out, S_LEN, 2048, HID,
                                                 nullptr, nullptr, nullptr, nullptr, nullptr);
}